// Round 1
// baseline (114.611 us; speedup 1.0000x reference)
//
#include <hip/hip_runtime.h>
#include <hip/hip_bf16.h>
#include <math.h>

#define B_ROWS 16384
#define DIM 1024

typedef __attribute__((ext_vector_type(8))) short s16x8;
typedef __attribute__((ext_vector_type(4))) float f32x4;

static __device__ __forceinline__ unsigned short f2bf(float f) {
    union { float f; unsigned u; } v; v.f = f;
    unsigned r = v.u + 0x7FFF + ((v.u >> 16) & 1);  // RNE
    return (unsigned short)(r >> 16);
}

// ---------------------------------------------------------------------------
// Kernel 0: convert + transpose + zero-pad weights into bf16 N x K layout.
//   W1 (1024x500 f32, KxN) -> W1b (512x1024 bf16, NxK), rows >=500 zero
//   W2 (500x200)           -> W2b (256x512),  n>=200 or k>=500 zero
//   W3 (200x200)           -> W3b (256x256),  n>=200 or k>=200 zero
// Zero pads guarantee padded d1/d2 columns come out exactly 0 downstream.
// ---------------------------------------------------------------------------
__global__ void convert_weights(const float* __restrict__ W1,
                                const float* __restrict__ W2,
                                const float* __restrict__ W3,
                                unsigned short* __restrict__ W1b,
                                unsigned short* __restrict__ W2b,
                                unsigned short* __restrict__ W3b) {
    const int id = blockIdx.x * 256 + threadIdx.x;
    if (id < 512 * 1024) {
        const int n = id >> 10, k = id & 1023;
        const float v = (n < 500) ? W1[k * 500 + n] : 0.f;
        W1b[id] = f2bf(v);
    } else if (id < 512 * 1024 + 256 * 512) {
        const int j = id - 512 * 1024;
        const int n = j >> 9, k = j & 511;
        const float v = (n < 200 && k < 500) ? W2[k * 200 + n] : 0.f;
        W2b[j] = f2bf(v);
    } else {
        const int j = id - (512 * 1024 + 256 * 512);
        const int n = j >> 8, k = j & 255;
        const float v = (n < 200 && k < 200) ? W3[k * 200 + n] : 0.f;
        W3b[j] = f2bf(v);
    }
}

// ---------------------------------------------------------------------------
// GEMM + bias + ReLU -> bf16 out.  Tile 128x128, BK=32, 4 waves (2x2),
// mfma_f32_16x16x32_bf16.  B stored N x K (pre-transposed), so A and B LDS
// tiles are both [128 rows][32 k] bf16 with identical XOR-swizzled layout.
// A is f32 (converted in staging) or bf16 per template arg.
// ---------------------------------------------------------------------------
template <bool A_F32>
__global__ __launch_bounds__(256) void gemm_bias_relu(
    const void* __restrict__ Aptr,
    const unsigned short* __restrict__ Bw,   // ldc x K bf16, N-major
    const float* __restrict__ bias, int biasN,
    unsigned short* __restrict__ C,          // M x ldc bf16
    int K, int ldc) {
    __shared__ unsigned short As[128 * 32];
    __shared__ unsigned short Bs[128 * 32];

    const int tid  = threadIdx.x;
    const int lane = tid & 63;
    const int wid  = tid >> 6;
    const int wm   = wid >> 1;
    const int wn   = wid & 1;
    const int nColTiles = ldc >> 7;
    const int bm = blockIdx.x / nColTiles;   // col tiles fastest -> L2 row reuse
    const int bn = blockIdx.x % nColTiles;
    const int rowBase = bm << 7;
    const int colBase = bn << 7;

    const int sRow  = tid >> 1;   // 0..127
    const int sHalf = tid & 1;    // k half (16 elems)

    f32x4 acc[4][4];
#pragma unroll
    for (int m = 0; m < 4; ++m)
#pragma unroll
        for (int n = 0; n < 4; ++n)
            acc[m][n] = (f32x4){0.f, 0.f, 0.f, 0.f};

    const int g   = lane >> 4;
    const int r16 = lane & 15;

    const int nK = K >> 5;
    for (int kt = 0; kt < nK; ++kt) {
        const int k0 = kt << 5;
        unsigned short abuf[16];
        if constexpr (A_F32) {
            const float* src = (const float*)Aptr + (size_t)(rowBase + sRow) * K + k0 + sHalf * 16;
#pragma unroll
            for (int c = 0; c < 4; ++c) {
                float4 f = *(const float4*)(src + c * 4);
                abuf[c * 4 + 0] = f2bf(f.x);
                abuf[c * 4 + 1] = f2bf(f.y);
                abuf[c * 4 + 2] = f2bf(f.z);
                abuf[c * 4 + 3] = f2bf(f.w);
            }
        } else {
            const unsigned short* src =
                (const unsigned short*)Aptr + (size_t)(rowBase + sRow) * K + k0 + sHalf * 16;
            *(int4*)&abuf[0] = *(const int4*)(src);
            *(int4*)&abuf[8] = *(const int4*)(src + 8);
        }
        unsigned short bbuf[16];
        {
            const unsigned short* src = Bw + (size_t)(colBase + sRow) * K + k0 + sHalf * 16;
            *(int4*)&bbuf[0] = *(const int4*)(src);
            *(int4*)&bbuf[8] = *(const int4*)(src + 8);
        }
#pragma unroll
        for (int c2 = 0; c2 < 2; ++c2) {
            const int off = (sHalf * 32 + c2 * 16) ^ ((sRow & 3) << 4);
            *(int4*)((char*)As + sRow * 64 + off) = *(int4*)&abuf[c2 * 8];
            *(int4*)((char*)Bs + sRow * 64 + off) = *(int4*)&bbuf[c2 * 8];
        }
        __syncthreads();

        s16x8 af[4], bfr[4];
#pragma unroll
        for (int m = 0; m < 4; ++m) {
            const int row = wm * 64 + m * 16 + r16;
            const int off = (g * 16) ^ ((row & 3) << 4);
            af[m] = *(const s16x8*)((const char*)As + row * 64 + off);
        }
#pragma unroll
        for (int n = 0; n < 4; ++n) {
            const int row = wn * 64 + n * 16 + r16;
            const int off = (g * 16) ^ ((row & 3) << 4);
            bfr[n] = *(const s16x8*)((const char*)Bs + row * 64 + off);
        }
#pragma unroll
        for (int m = 0; m < 4; ++m)
#pragma unroll
            for (int n = 0; n < 4; ++n)
                acc[m][n] = __builtin_amdgcn_mfma_f32_16x16x32_bf16(af[m], bfr[n], acc[m][n], 0, 0, 0);
        __syncthreads();
    }

    // epilogue: bias + relu + bf16 store.  D: row=(lane>>4)*4+r, col=lane&15
#pragma unroll
    for (int n = 0; n < 4; ++n) {
        const int col = colBase + wn * 64 + n * 16 + r16;
        const float bv = (col < biasN) ? bias[col] : 0.f;
#pragma unroll
        for (int m = 0; m < 4; ++m) {
            const int rowB = rowBase + wm * 64 + m * 16 + g * 4;
#pragma unroll
            for (int r = 0; r < 4; ++r) {
                float v = acc[m][n][r] + bv;
                v = v > 0.f ? v : 0.f;
                C[(size_t)(rowB + r) * ldc + col] = f2bf(v);
            }
        }
    }
}

// ---------------------------------------------------------------------------
// GEMM3 fused with tail dot:  tail[b] = relu(d2@W3 + b3) . Wl[1024:1224]
// Block: 64 rows x 256 cols (full padded N), 4 waves side-by-side in N.
// d3 never hits memory.
// ---------------------------------------------------------------------------
__global__ __launch_bounds__(256) void gemm3_tail(
    const unsigned short* __restrict__ d2,   // M x 256 bf16
    const unsigned short* __restrict__ W3b,  // 256 x 256 bf16 (N x K)
    const float* __restrict__ b3,
    const float* __restrict__ Wl,            // 1224 floats
    float* __restrict__ tail) {
    __shared__ unsigned short As[64 * 32];
    __shared__ unsigned short Bs[256 * 32];
    __shared__ float part[4][64];

    const int tid  = threadIdx.x;
    const int lane = tid & 63;
    const int wid  = tid >> 6;
    const int rowBase = blockIdx.x << 6;

    const int g   = lane >> 4;
    const int r16 = lane & 15;

    f32x4 acc[4][4];
#pragma unroll
    for (int m = 0; m < 4; ++m)
#pragma unroll
        for (int n = 0; n < 4; ++n)
            acc[m][n] = (f32x4){0.f, 0.f, 0.f, 0.f};

    for (int kt = 0; kt < 8; ++kt) {
        const int k0 = kt << 5;
        {
            const int ar = tid >> 2, ac = tid & 3;
            int4 v = *(const int4*)(d2 + (size_t)(rowBase + ar) * 256 + k0 + ac * 8);
            const int off = (ac * 16) ^ ((ar & 3) << 4);
            *(int4*)((char*)As + ar * 64 + off) = v;
        }
        {
            const int n = tid;
#pragma unroll
            for (int c = 0; c < 4; ++c) {
                int4 v = *(const int4*)(W3b + (size_t)n * 256 + k0 + c * 8);
                const int off = (c * 16) ^ ((n & 3) << 4);
                *(int4*)((char*)Bs + n * 64 + off) = v;
            }
        }
        __syncthreads();

        s16x8 af[4], bfr[4];
#pragma unroll
        for (int m = 0; m < 4; ++m) {
            const int row = m * 16 + r16;
            const int off = (g * 16) ^ ((row & 3) << 4);
            af[m] = *(const s16x8*)((const char*)As + row * 64 + off);
        }
#pragma unroll
        for (int n = 0; n < 4; ++n) {
            const int row = wid * 64 + n * 16 + r16;
            const int off = (g * 16) ^ ((row & 3) << 4);
            bfr[n] = *(const s16x8*)((const char*)Bs + row * 64 + off);
        }
#pragma unroll
        for (int m = 0; m < 4; ++m)
#pragma unroll
            for (int n = 0; n < 4; ++n)
                acc[m][n] = __builtin_amdgcn_mfma_f32_16x16x32_bf16(af[m], bfr[n], acc[m][n], 0, 0, 0);
        __syncthreads();
    }

    float wlv[4], b3v[4];
#pragma unroll
    for (int n = 0; n < 4; ++n) {
        const int col = wid * 64 + n * 16 + r16;
        wlv[n] = (col < 200) ? Wl[1024 + col] : 0.f;
        b3v[n] = (col < 200) ? b3[col] : 0.f;
    }
#pragma unroll
    for (int m = 0; m < 4; ++m) {
#pragma unroll
        for (int r = 0; r < 4; ++r) {
            float s = 0.f;
#pragma unroll
            for (int n = 0; n < 4; ++n) {
                float v = acc[m][n][r] + b3v[n];
                v = v > 0.f ? v : 0.f;
                s += v * wlv[n];
            }
            s += __shfl_xor(s, 1, 64);
            s += __shfl_xor(s, 2, 64);
            s += __shfl_xor(s, 4, 64);
            s += __shfl_xor(s, 8, 64);
            if (r16 == 0) part[wid][m * 16 + g * 4 + r] = s;
        }
    }
    __syncthreads();
    if (tid < 64)
        tail[rowBase + tid] = part[0][tid] + part[1][tid] + part[2][tid] + part[3][tid];
}

// ---------------------------------------------------------------------------
// Cross-net + final sigmoid head, one wave per row, all in registers (fp32).
// emb_{j+1}[k] = xsum*emb_j[k]*cw[i,j,k] + cb[i,j,k] + x[k]
// out[i*B + b]  = sigmoid(emb3 . Wl[:1024] + tail[b] + bl)
// ---------------------------------------------------------------------------
__global__ __launch_bounds__(256) void cross_final(
    const float* __restrict__ x,
    const float* __restrict__ cw, const float* __restrict__ cb,
    const float* __restrict__ Wl, const float* __restrict__ bl,
    const float* __restrict__ tail,
    float* __restrict__ out) {
    const int tid  = threadIdx.x;
    const int lane = tid & 63;
    const int wid  = tid >> 6;
    const int row  = (blockIdx.x << 2) + wid;

    const float* xr = x + (size_t)row * DIM;
    float xv[16];
#pragma unroll
    for (int c = 0; c < 4; ++c)
        *(float4*)&xv[c * 4] = *(const float4*)(xr + c * 256 + lane * 4);

    float xs = 0.f;
#pragma unroll
    for (int t = 0; t < 16; ++t) xs += xv[t];
#pragma unroll
    for (int m = 1; m < 64; m <<= 1) xs += __shfl_xor(xs, m, 64);

    float wlv[16];
#pragma unroll
    for (int c = 0; c < 4; ++c)
        *(float4*)&wlv[c * 4] = *(const float4*)(Wl + c * 256 + lane * 4);

    const float tl  = tail[row];
    const float blv = bl[0];

#pragma unroll
    for (int i = 0; i < 2; ++i) {
        float e[16];
#pragma unroll
        for (int t = 0; t < 16; ++t) e[t] = xv[t];
#pragma unroll
        for (int j = 0; j < 3; ++j) {
            const float* cwp = cw + (size_t)(i * 3 + j) * DIM;
            const float* cbp = cb + (size_t)(i * 3 + j) * DIM;
#pragma unroll
            for (int c = 0; c < 4; ++c) {
                float wv[4], bv[4];
                *(float4*)wv = *(const float4*)(cwp + c * 256 + lane * 4);
                *(float4*)bv = *(const float4*)(cbp + c * 256 + lane * 4);
#pragma unroll
                for (int q = 0; q < 4; ++q) {
                    const int t = c * 4 + q;
                    e[t] = xs * e[t] * wv[q] + bv[q] + xv[t];
                }
            }
        }
        float z = 0.f;
#pragma unroll
        for (int t = 0; t < 16; ++t) z += e[t] * wlv[t];
#pragma unroll
        for (int m = 1; m < 64; m <<= 1) z += __shfl_xor(z, m, 64);
        z += tl + blv;
        if (lane == 0) out[(size_t)i * B_ROWS + row] = 1.f / (1.f + expf(-z));
    }
}

// ---------------------------------------------------------------------------
extern "C" void kernel_launch(void* const* d_in, const int* in_sizes, int n_in,
                              void* d_out, int out_size, void* d_ws, size_t ws_size,
                              hipStream_t stream) {
    const float* x  = (const float*)d_in[0];
    // d_in[1] show_index, d_in[2] st: unused by the reference computation
    const float* W1 = (const float*)d_in[3];
    const float* b1 = (const float*)d_in[4];
    const float* W2 = (const float*)d_in[5];
    const float* b2 = (const float*)d_in[6];
    const float* W3 = (const float*)d_in[7];
    const float* b3 = (const float*)d_in[8];
    const float* Wl = (const float*)d_in[9];
    const float* bl = (const float*)d_in[10];
    const float* cw = (const float*)d_in[11];
    const float* cb = (const float*)d_in[12];
    float* out = (float*)d_out;

    // workspace layout (bf16 = unsigned short), ~26 MiB total
    unsigned short* d1  = (unsigned short*)d_ws;          // 16384 x 512
    unsigned short* d2  = d1 + (size_t)16384 * 512;       // 16384 x 256
    unsigned short* W1b = d2 + (size_t)16384 * 256;       // 512 x 1024
    unsigned short* W2b = W1b + (size_t)512 * 1024;       // 256 x 512
    unsigned short* W3b = W2b + (size_t)256 * 512;        // 256 x 256
    float* tail = (float*)(W3b + (size_t)256 * 256);      // 16384

    // total elems 512*1024 + 256*512 + 256*256 = 720896 = 2816 * 256
    convert_weights<<<2816, 256, 0, stream>>>(W1, W2, W3, W1b, W2b, W3b);

    // d1 = relu(x @ W1 + b1): M=16384, K=1024, ldc=512 (cols>=500 are 0)
    gemm_bias_relu<true><<<128 * 4, 256, 0, stream>>>(x, W1b, b1, 500, d1, 1024, 512);

    // d2 = relu(d1 @ W2 + b2): K=512, ldc=256 (cols>=200 are 0)
    gemm_bias_relu<false><<<128 * 2, 256, 0, stream>>>(d1, W2b, b2, 200, d2, 512, 256);

    // tail = relu(d2 @ W3 + b3) . Wl[1024:]
    gemm3_tail<<<256, 256, 0, stream>>>(d2, W3b, b3, Wl, tail);

    // cross net + sigmoid head
    cross_final<<<4096, 256, 0, stream>>>(x, cw, cb, Wl, bl, tail, out);
}

// Round 2
// 95.856 us; speedup vs baseline: 1.1957x; 1.1957x over previous
//
#include <hip/hip_runtime.h>
#include <hip/hip_bf16.h>
#include <math.h>

#define B_ROWS 16384
#define DIM 1024

typedef __attribute__((ext_vector_type(8))) short s16x8;
typedef __attribute__((ext_vector_type(4))) short s16x4;
typedef __attribute__((ext_vector_type(4))) float f32x4;

static __device__ __forceinline__ unsigned short f2bf(float f) {
    union { float f; unsigned u; } v; v.f = f;
    unsigned r = v.u + 0x7FFF + ((v.u >> 16) & 1);  // RNE
    return (unsigned short)(r >> 16);
}
static __device__ __forceinline__ float bf2f(unsigned short h) {
    union { unsigned u; float f; } v; v.u = ((unsigned)h) << 16;
    return v.f;
}

// async global -> LDS, 16 bytes per lane.  lds ptr must be wave-uniform;
// HW writes lds_base + lane*16.
static __device__ __forceinline__ void gload16(const unsigned short* g, unsigned short* l) {
    __builtin_amdgcn_global_load_lds(
        (const __attribute__((address_space(1))) unsigned int*)g,
        (__attribute__((address_space(3))) unsigned int*)l, 16, 0, 0);
}

// ---------------------------------------------------------------------------
// prep: x (f32) -> xb (bf16) + exact f32 row sums; also weight convert+pad.
// Blocks [0,4096): 4 waves/block, one row each.  Blocks [4096,6912): weights.
// ---------------------------------------------------------------------------
__global__ __launch_bounds__(256) void prep(
    const float* __restrict__ x, unsigned short* __restrict__ xb,
    float* __restrict__ xsum,
    const float* __restrict__ W1, const float* __restrict__ W2,
    const float* __restrict__ W3,
    unsigned short* __restrict__ W1b, unsigned short* __restrict__ W2b,
    unsigned short* __restrict__ W3b) {
    const int tid = threadIdx.x;
    if (blockIdx.x < 4096) {
        const int lane = tid & 63;
        const int wid  = tid >> 6;
        const int row  = (blockIdx.x << 2) + wid;
        const float* xr = x + (size_t)row * DIM;
        unsigned short* xo = xb + (size_t)row * DIM;
        float s = 0.f;
#pragma unroll
        for (int c = 0; c < 4; ++c) {
            float4 f = *(const float4*)(xr + c * 256 + lane * 4);
            s += f.x + f.y + f.z + f.w;
            short4 h;
            h.x = (short)f2bf(f.x); h.y = (short)f2bf(f.y);
            h.z = (short)f2bf(f.z); h.w = (short)f2bf(f.w);
            *(short4*)(xo + c * 256 + lane * 4) = h;
        }
#pragma unroll
        for (int m = 1; m < 64; m <<= 1) s += __shfl_xor(s, m, 64);
        if (lane == 0) xsum[row] = s;
    } else {
        const int id = (blockIdx.x - 4096) * 256 + tid;
        if (id < 512 * 1024) {
            const int n = id >> 10, k = id & 1023;
            W1b[id] = f2bf((n < 500) ? W1[k * 500 + n] : 0.f);
        } else if (id < 512 * 1024 + 256 * 512) {
            const int j = id - 512 * 1024;
            const int n = j >> 9, k = j & 511;
            W2b[j] = f2bf((n < 200 && k < 500) ? W2[k * 200 + n] : 0.f);
        } else {
            const int j = id - (512 * 1024 + 256 * 512);
            const int n = j >> 8, k = j & 255;
            W3b[j] = f2bf((n < 200 && k < 200) ? W3[k * 200 + n] : 0.f);
        }
    }
}

// ---------------------------------------------------------------------------
// bf16 GEMM + bias + ReLU, tile BM x 128, BK=64, 4 waves (2x2).
// Both operands N x K row-major bf16.  Staging: global_load_lds dwordx4 with
// pre-swizzled global source (LDS dest linear); LDS logical layout:
// LDS[row][slot(16B)] holds k-chunk (slot ^ (row&7)) -> conflict-free-ish
// ds_read_b128.  Double-buffered, counted vmcnt, raw s_barrier.
// ---------------------------------------------------------------------------
template <int ROWS>
static __device__ __forceinline__ void stage_tile(
    const unsigned short* __restrict__ src, int K, int rowBase, int kt,
    unsigned short* lds, int w, int lane) {
    const int r8   = lane >> 3;   // row within 8-row group
    const int slot = lane & 7;
#pragma unroll
    for (int q = 0; q < ROWS / 32; ++q) {
        const int blk   = q * 4 + w;
        const int row   = blk * 8 + r8;
        const int chunk = slot ^ (row & 7);
        const unsigned short* g = src + (size_t)(rowBase + row) * K + kt * 64 + chunk * 8;
        gload16(g, lds + blk * 512);
    }
}

template <int BM>
__global__ __launch_bounds__(256) void gemm_bf16(
    const unsigned short* __restrict__ A,    // M x K bf16
    const unsigned short* __restrict__ Bw,   // ldc x K bf16 (N-major)
    const float* __restrict__ bias, int biasN,
    unsigned short* __restrict__ C,          // M x ldc bf16
    int K, int ldc) {
    constexpr int MREP = BM / 32;
    __shared__ unsigned short As[2][BM * 64];
    __shared__ unsigned short Bs[2][128 * 64];

    const int tid  = threadIdx.x;
    const int lane = tid & 63;
    const int wid  = tid >> 6;
    const int wm   = wid >> 1;
    const int wn   = wid & 1;
    const int g    = lane >> 4;
    const int r16  = lane & 15;

    // XCD-aware bijective swizzle (gridDim divisible by 8)
    const int cpx = gridDim.x >> 3;
    const int swz = (blockIdx.x & 7) * cpx + (blockIdx.x >> 3);
    const int nColTiles = ldc >> 7;
    const int rowBase = (swz / nColTiles) * BM;
    const int colBase = (swz % nColTiles) << 7;

    f32x4 acc[MREP][4];
#pragma unroll
    for (int m = 0; m < MREP; ++m)
#pragma unroll
        for (int n = 0; n < 4; ++n)
            acc[m][n] = (f32x4){0.f, 0.f, 0.f, 0.f};

    stage_tile<BM>(A, K, rowBase, 0, As[0], wid, lane);
    stage_tile<128>(Bw, K, colBase, 0, Bs[0], wid, lane);

    const int nK = K >> 6;
    for (int kt = 0; kt < nK; ++kt) {
        const int buf = kt & 1;
        if (kt + 1 < nK) {
            stage_tile<BM>(A, K, rowBase, kt + 1, As[buf ^ 1], wid, lane);
            stage_tile<128>(Bw, K, colBase, kt + 1, Bs[buf ^ 1], wid, lane);
            if constexpr (BM == 128)
                asm volatile("s_waitcnt vmcnt(8)" ::: "memory");
            else
                asm volatile("s_waitcnt vmcnt(6)" ::: "memory");
        } else {
            asm volatile("s_waitcnt vmcnt(0)" ::: "memory");
        }
        __builtin_amdgcn_s_barrier();
        asm volatile("" ::: "memory");

        const unsigned short* Ab = As[buf];
        const unsigned short* Bb = Bs[buf];
#pragma unroll
        for (int ks = 0; ks < 2; ++ks) {
            s16x8 af[MREP], bfr[4];
#pragma unroll
            for (int m = 0; m < MREP; ++m) {
                const int row = wm * (BM / 2) + m * 16 + r16;
                const int off = ((ks * 4 + g) * 16) ^ ((row & 7) << 4);
                af[m] = *(const s16x8*)((const char*)Ab + row * 128 + off);
            }
#pragma unroll
            for (int n = 0; n < 4; ++n) {
                const int row = wn * 64 + n * 16 + r16;
                const int off = ((ks * 4 + g) * 16) ^ ((row & 7) << 4);
                bfr[n] = *(const s16x8*)((const char*)Bb + row * 128 + off);
            }
#pragma unroll
            for (int m = 0; m < MREP; ++m)
#pragma unroll
                for (int n = 0; n < 4; ++n)
                    acc[m][n] = __builtin_amdgcn_mfma_f32_16x16x32_bf16(af[m], bfr[n], acc[m][n], 0, 0, 0);
        }
        asm volatile("s_waitcnt lgkmcnt(0)" ::: "memory");
        __builtin_amdgcn_s_barrier();
        asm volatile("" ::: "memory");
    }

    // epilogue: bias + relu + bf16 store.  D: col=lane&15, row=(lane>>4)*4+r
#pragma unroll
    for (int n = 0; n < 4; ++n) {
        const int col = colBase + wn * 64 + n * 16 + r16;
        const float bv = (col < biasN) ? bias[col] : 0.f;
#pragma unroll
        for (int m = 0; m < MREP; ++m) {
            const int rowB = rowBase + wm * (BM / 2) + m * 16 + g * 4;
#pragma unroll
            for (int r = 0; r < 4; ++r) {
                float v = acc[m][n][r] + bv;
                v = v > 0.f ? v : 0.f;
                C[(size_t)(rowB + r) * ldc + col] = f2bf(v);
            }
        }
    }
}

// ---------------------------------------------------------------------------
// GEMM3 fused with tail dot:  tail[b] = relu(d2@W3 + b3) . Wl[1024:1224]
// Block: 64 rows x 256 cols (full padded N), 4 waves side-by-side in N.
// ---------------------------------------------------------------------------
__global__ __launch_bounds__(256) void gemm3_tail(
    const unsigned short* __restrict__ d2,   // M x 256 bf16
    const unsigned short* __restrict__ W3b,  // 256 x 256 bf16 (N x K)
    const float* __restrict__ b3,
    const float* __restrict__ Wl,            // 1224 floats
    float* __restrict__ tail) {
    __shared__ unsigned short As[64 * 32];
    __shared__ unsigned short Bs[256 * 32];
    __shared__ float part[4][64];

    const int tid  = threadIdx.x;
    const int lane = tid & 63;
    const int wid  = tid >> 6;
    const int rowBase = blockIdx.x << 6;

    const int g   = lane >> 4;
    const int r16 = lane & 15;

    f32x4 acc[4][4];
#pragma unroll
    for (int m = 0; m < 4; ++m)
#pragma unroll
        for (int n = 0; n < 4; ++n)
            acc[m][n] = (f32x4){0.f, 0.f, 0.f, 0.f};

    for (int kt = 0; kt < 8; ++kt) {
        const int k0 = kt << 5;
        {
            const int ar = tid >> 2, ac = tid & 3;
            int4 v = *(const int4*)(d2 + (size_t)(rowBase + ar) * 256 + k0 + ac * 8);
            const int off = (ac * 16) ^ ((ar & 3) << 4);
            *(int4*)((char*)As + ar * 64 + off) = v;
        }
        {
            const int n = tid;
#pragma unroll
            for (int c = 0; c < 4; ++c) {
                int4 v = *(const int4*)(W3b + (size_t)n * 256 + k0 + c * 8);
                const int off = (c * 16) ^ ((n & 3) << 4);
                *(int4*)((char*)Bs + n * 64 + off) = v;
            }
        }
        __syncthreads();

        s16x8 af[4], bfr[4];
#pragma unroll
        for (int m = 0; m < 4; ++m) {
            const int row = m * 16 + r16;
            const int off = (g * 16) ^ ((row & 3) << 4);
            af[m] = *(const s16x8*)((const char*)As + row * 64 + off);
        }
#pragma unroll
        for (int n = 0; n < 4; ++n) {
            const int row = wid * 64 + n * 16 + r16;
            const int off = (g * 16) ^ ((row & 3) << 4);
            bfr[n] = *(const s16x8*)((const char*)Bs + row * 64 + off);
        }
#pragma unroll
        for (int m = 0; m < 4; ++m)
#pragma unroll
            for (int n = 0; n < 4; ++n)
                acc[m][n] = __builtin_amdgcn_mfma_f32_16x16x32_bf16(af[m], bfr[n], acc[m][n], 0, 0, 0);
        __syncthreads();
    }

    float wlv[4], b3v[4];
#pragma unroll
    for (int n = 0; n < 4; ++n) {
        const int col = wid * 64 + n * 16 + r16;
        wlv[n] = (col < 200) ? Wl[1024 + col] : 0.f;
        b3v[n] = (col < 200) ? b3[col] : 0.f;
    }
#pragma unroll
    for (int m = 0; m < 4; ++m) {
#pragma unroll
        for (int r = 0; r < 4; ++r) {
            float s = 0.f;
#pragma unroll
            for (int n = 0; n < 4; ++n) {
                float v = acc[m][n][r] + b3v[n];
                v = v > 0.f ? v : 0.f;
                s += v * wlv[n];
            }
            s += __shfl_xor(s, 1, 64);
            s += __shfl_xor(s, 2, 64);
            s += __shfl_xor(s, 4, 64);
            s += __shfl_xor(s, 8, 64);
            if (r16 == 0) part[wid][m * 16 + g * 4 + r] = s;
        }
    }
    __syncthreads();
    if (tid < 64)
        tail[rowBase + tid] = part[0][tid] + part[1][tid] + part[2][tid] + part[3][tid];
}

// ---------------------------------------------------------------------------
// Cross-net + final sigmoid head, one wave per row, registers only.
// Reads bf16 x (halved traffic) + exact f32 xsum from prep.
// ---------------------------------------------------------------------------
__global__ __launch_bounds__(256) void cross_final(
    const unsigned short* __restrict__ xb,
    const float* __restrict__ xsum,
    const float* __restrict__ cw, const float* __restrict__ cb,
    const float* __restrict__ Wl, const float* __restrict__ bl,
    const float* __restrict__ tail,
    float* __restrict__ out) {
    const int tid  = threadIdx.x;
    const int lane = tid & 63;
    const int wid  = tid >> 6;
    const int row  = (blockIdx.x << 2) + wid;

    const unsigned short* xr = xb + (size_t)row * DIM;
    float xv[16];
#pragma unroll
    for (int c = 0; c < 4; ++c) {
        s16x4 h = *(const s16x4*)(xr + c * 256 + lane * 4);
#pragma unroll
        for (int q = 0; q < 4; ++q) xv[c * 4 + q] = bf2f((unsigned short)h[q]);
    }

    const float xs = xsum[row];

    float wlv[16];
#pragma unroll
    for (int c = 0; c < 4; ++c)
        *(float4*)&wlv[c * 4] = *(const float4*)(Wl + c * 256 + lane * 4);

    const float tl  = tail[row];
    const float blv = bl[0];

#pragma unroll
    for (int i = 0; i < 2; ++i) {
        float e[16];
#pragma unroll
        for (int t = 0; t < 16; ++t) e[t] = xv[t];
#pragma unroll
        for (int j = 0; j < 3; ++j) {
            const float* cwp = cw + (size_t)(i * 3 + j) * DIM;
            const float* cbp = cb + (size_t)(i * 3 + j) * DIM;
#pragma unroll
            for (int c = 0; c < 4; ++c) {
                float wv[4], bv[4];
                *(float4*)wv = *(const float4*)(cwp + c * 256 + lane * 4);
                *(float4*)bv = *(const float4*)(cbp + c * 256 + lane * 4);
#pragma unroll
                for (int q = 0; q < 4; ++q) {
                    const int t = c * 4 + q;
                    e[t] = xs * e[t] * wv[q] + bv[q] + xv[t];
                }
            }
        }
        float z = 0.f;
#pragma unroll
        for (int t = 0; t < 16; ++t) z += e[t] * wlv[t];
#pragma unroll
        for (int m = 1; m < 64; m <<= 1) z += __shfl_xor(z, m, 64);
        z += tl + blv;
        if (lane == 0) out[(size_t)i * B_ROWS + row] = 1.f / (1.f + expf(-z));
    }
}

// ---------------------------------------------------------------------------
extern "C" void kernel_launch(void* const* d_in, const int* in_sizes, int n_in,
                              void* d_out, int out_size, void* d_ws, size_t ws_size,
                              hipStream_t stream) {
    const float* x  = (const float*)d_in[0];
    const float* W1 = (const float*)d_in[3];
    const float* b1 = (const float*)d_in[4];
    const float* W2 = (const float*)d_in[5];
    const float* b2 = (const float*)d_in[6];
    const float* W3 = (const float*)d_in[7];
    const float* b3 = (const float*)d_in[8];
    const float* Wl = (const float*)d_in[9];
    const float* bl = (const float*)d_in[10];
    const float* cw = (const float*)d_in[11];
    const float* cb = (const float*)d_in[12];
    float* out = (float*)d_out;

    // workspace layout (bf16 = unsigned short), ~60.3 MiB total
    unsigned short* xb  = (unsigned short*)d_ws;          // 16384 x 1024
    unsigned short* d1  = xb + (size_t)16384 * 1024;      // 16384 x 512
    unsigned short* d2  = d1 + (size_t)16384 * 512;       // 16384 x 256
    unsigned short* W1b = d2 + (size_t)16384 * 256;       // 512 x 1024
    unsigned short* W2b = W1b + (size_t)512 * 1024;       // 256 x 512
    unsigned short* W3b = W2b + (size_t)256 * 512;        // 256 x 256
    float* xsum = (float*)(W3b + (size_t)256 * 256);      // 16384
    float* tail = xsum + 16384;                           // 16384

    // x convert + row sums (4096 blocks) + weight convert (2816 blocks)
    prep<<<4096 + 2816, 256, 0, stream>>>(x, xb, xsum, W1, W2, W3, W1b, W2b, W3b);

    // d1 = relu(xb @ W1 + b1): M=16384, K=1024, ldc=512
    gemm_bf16<128><<<512, 256, 0, stream>>>(xb, W1b, b1, 500, d1, 1024, 512);

    // d2 = relu(d1 @ W2 + b2): K=512, ldc=256
    gemm_bf16<64><<<512, 256, 0, stream>>>(d1, W2b, b2, 200, d2, 512, 256);

    // tail = relu(d2 @ W3 + b3) . Wl[1024:]
    gemm3_tail<<<256, 256, 0, stream>>>(d2, W3b, b3, Wl, tail);

    // cross net + sigmoid head
    cross_final<<<4096, 256, 0, stream>>>(xb, xsum, cw, cb, Wl, bl, tail, out);
}

// Round 3
// 92.141 us; speedup vs baseline: 1.2439x; 1.0403x over previous
//
#include <hip/hip_runtime.h>
#include <hip/hip_bf16.h>
#include <math.h>

#define B_ROWS 16384
#define DIM 1024

typedef __attribute__((ext_vector_type(8))) short s16x8;
typedef __attribute__((ext_vector_type(4))) short s16x4;
typedef __attribute__((ext_vector_type(4))) float f32x4;

static __device__ __forceinline__ unsigned short f2bf(float f) {
    union { float f; unsigned u; } v; v.f = f;
    unsigned r = v.u + 0x7FFF + ((v.u >> 16) & 1);  // RNE
    return (unsigned short)(r >> 16);
}

// async global -> LDS, 16 bytes per lane; lds base wave-uniform, HW adds lane*16
static __device__ __forceinline__ void gload16(const unsigned short* g, unsigned short* l) {
    __builtin_amdgcn_global_load_lds(
        (const __attribute__((address_space(1))) unsigned int*)g,
        (__attribute__((address_space(3))) unsigned int*)l, 16, 0, 0);
}

// ---------------------------------------------------------------------------
// prep: blocks [0,4096): x rows — convert x->xb (bf16) AND compute the whole
//   cross-net partial logit zc[i][row] = emb3(i) . Wl[:1024]  (all f32, x is
//   in registers anyway).  blocks [4096,4272): weight transpose+convert+pad
//   via 64x64 LDS tiles (coalesced both sides).
// ---------------------------------------------------------------------------
__global__ __launch_bounds__(256) void prep(
    const float* __restrict__ x, unsigned short* __restrict__ xb,
    const float* __restrict__ cw, const float* __restrict__ cb,
    const float* __restrict__ Wl,
    float* __restrict__ zc,                   // 2 * B_ROWS
    const float* __restrict__ W1, const float* __restrict__ W2,
    const float* __restrict__ W3,
    unsigned short* __restrict__ W1b, unsigned short* __restrict__ W2b,
    unsigned short* __restrict__ W3b) {
    __shared__ unsigned short tile[64][72];   // weight-transpose scratch
    const int tid = threadIdx.x;

    if (blockIdx.x < 4096) {
        const int lane = tid & 63;
        const int wid  = tid >> 6;
        const int row  = (blockIdx.x << 2) + wid;
        const float* xr = x + (size_t)row * DIM;
        unsigned short* xo = xb + (size_t)row * DIM;

        float xv[16];
#pragma unroll
        for (int c = 0; c < 4; ++c)
            *(float4*)&xv[c * 4] = *(const float4*)(xr + c * 256 + lane * 4);

        // bf16 copy for GEMM1
#pragma unroll
        for (int c = 0; c < 4; ++c) {
            short4 h;
            h.x = (short)f2bf(xv[c * 4 + 0]); h.y = (short)f2bf(xv[c * 4 + 1]);
            h.z = (short)f2bf(xv[c * 4 + 2]); h.w = (short)f2bf(xv[c * 4 + 3]);
            *(short4*)(xo + c * 256 + lane * 4) = h;
        }

        float xs = 0.f;
#pragma unroll
        for (int t = 0; t < 16; ++t) xs += xv[t];
#pragma unroll
        for (int m = 1; m < 64; m <<= 1) xs += __shfl_xor(xs, m, 64);

        float wlv[16];
#pragma unroll
        for (int c = 0; c < 4; ++c)
            *(float4*)&wlv[c * 4] = *(const float4*)(Wl + c * 256 + lane * 4);

#pragma unroll
        for (int i = 0; i < 2; ++i) {
            float e[16];
#pragma unroll
            for (int t = 0; t < 16; ++t) e[t] = xv[t];
#pragma unroll
            for (int j = 0; j < 3; ++j) {
                const float* cwp = cw + (size_t)(i * 3 + j) * DIM;
                const float* cbp = cb + (size_t)(i * 3 + j) * DIM;
#pragma unroll
                for (int c = 0; c < 4; ++c) {
                    float wv[4], bv[4];
                    *(float4*)wv = *(const float4*)(cwp + c * 256 + lane * 4);
                    *(float4*)bv = *(const float4*)(cbp + c * 256 + lane * 4);
#pragma unroll
                    for (int q = 0; q < 4; ++q) {
                        const int t = c * 4 + q;
                        e[t] = xs * e[t] * wv[q] + bv[q] + xv[t];
                    }
                }
            }
            float z = 0.f;
#pragma unroll
            for (int t = 0; t < 16; ++t) z += e[t] * wlv[t];
#pragma unroll
            for (int m = 1; m < 64; m <<= 1) z += __shfl_xor(z, m, 64);
            if (lane == 0) zc[(size_t)i * B_ROWS + row] = z;
        }
    } else {
        // ---- weight transpose: one 64(k) x 64(n) tile per block ----
        const int w = blockIdx.x - 4096;
        const float* src; unsigned short* dst;
        int kt, nt, Ksrc, Nsrc, ldDst;
        if (w < 128)      { kt = w & 15;        nt = w >> 4;        src = W1; dst = W1b; Ksrc = 1024; Nsrc = 500; ldDst = 1024; }
        else if (w < 160) { kt = (w - 128) & 7; nt = (w - 128) >> 3; src = W2; dst = W2b; Ksrc = 500;  Nsrc = 200; ldDst = 512;  }
        else              { kt = (w - 160) & 3; nt = (w - 160) >> 2; src = W3; dst = W3b; Ksrc = 200;  Nsrc = 200; ldDst = 256;  }
        const int k0 = kt << 6, n0 = nt << 6;
        // read: thread t covers row r=t>>2 (k), cols (t&3)*16..+15 (n); coalesced
        {
            const int r = tid >> 2, c0 = (tid & 3) << 4;
            const int kk = k0 + r;
#pragma unroll
            for (int i = 0; i < 16; ++i) {
                const int nn = n0 + c0 + i;
                const float v = (kk < Ksrc && nn < Nsrc) ? src[(size_t)kk * Nsrc + nn] : 0.f;
                tile[r][c0 + i] = f2bf(v);
            }
        }
        __syncthreads();
        // write: thread t covers col n=t>>2, k chunk (t&3)*16..+15; coalesced 32B
        {
            const int n = tid >> 2, kc = (tid & 3) << 4;
            unsigned short* o = dst + (size_t)(n0 + n) * ldDst + k0 + kc;
#pragma unroll
            for (int i = 0; i < 16; ++i) o[i] = tile[kc + i][n];
        }
    }
}

// ---------------------------------------------------------------------------
// bf16 GEMM + bias + ReLU, tile BM x 128, BK=64, 4 waves (BM/32 x 2).
// global_load_lds dwordx4 with pre-swizzled global source (linear LDS dest),
// XOR-swizzled ds_read_b128, double-buffered, counted vmcnt, raw s_barrier.
// ---------------------------------------------------------------------------
template <int ROWS>
static __device__ __forceinline__ void stage_tile(
    const unsigned short* __restrict__ src, int K, int rowBase, int kt,
    unsigned short* lds, int w, int lane) {
    const int r8   = lane >> 3;
    const int slot = lane & 7;
#pragma unroll
    for (int q = 0; q < ROWS / 32; ++q) {
        const int blk   = q * 4 + w;
        const int row   = blk * 8 + r8;
        const int chunk = slot ^ (row & 7);
        const unsigned short* g = src + (size_t)(rowBase + row) * K + kt * 64 + chunk * 8;
        gload16(g, lds + blk * 512);
    }
}

template <int BM>
__global__ __launch_bounds__(256) void gemm_bf16(
    const unsigned short* __restrict__ A,    // M x K bf16
    const unsigned short* __restrict__ Bw,   // ldc x K bf16 (N-major)
    const float* __restrict__ bias, int biasN,
    unsigned short* __restrict__ C,          // M x ldc bf16
    int K, int ldc) {
    constexpr int MREP = BM / 32;
    __shared__ unsigned short As[2][BM * 64];
    __shared__ unsigned short Bs[2][128 * 64];

    const int tid  = threadIdx.x;
    const int lane = tid & 63;
    const int wid  = tid >> 6;
    const int wm   = wid >> 1;
    const int wn   = wid & 1;
    const int g    = lane >> 4;
    const int r16  = lane & 15;

    // XCD-aware bijective swizzle (gridDim divisible by 8)
    const int cpx = gridDim.x >> 3;
    const int swz = (blockIdx.x & 7) * cpx + (blockIdx.x >> 3);
    const int nColTiles = ldc >> 7;
    const int rowBase = (swz / nColTiles) * BM;
    const int colBase = (swz % nColTiles) << 7;

    f32x4 acc[MREP][4];
#pragma unroll
    for (int m = 0; m < MREP; ++m)
#pragma unroll
        for (int n = 0; n < 4; ++n)
            acc[m][n] = (f32x4){0.f, 0.f, 0.f, 0.f};

    stage_tile<BM>(A, K, rowBase, 0, As[0], wid, lane);
    stage_tile<128>(Bw, K, colBase, 0, Bs[0], wid, lane);

    const int nK = K >> 6;
    for (int kt = 0; kt < nK; ++kt) {
        const int buf = kt & 1;
        if (kt + 1 < nK) {
            stage_tile<BM>(A, K, rowBase, kt + 1, As[buf ^ 1], wid, lane);
            stage_tile<128>(Bw, K, colBase, kt + 1, Bs[buf ^ 1], wid, lane);
            if constexpr (BM == 128)
                asm volatile("s_waitcnt vmcnt(8)" ::: "memory");
            else
                asm volatile("s_waitcnt vmcnt(6)" ::: "memory");
        } else {
            asm volatile("s_waitcnt vmcnt(0)" ::: "memory");
        }
        __builtin_amdgcn_s_barrier();
        asm volatile("" ::: "memory");

        const unsigned short* Ab = As[buf];
        const unsigned short* Bb = Bs[buf];
#pragma unroll
        for (int ks = 0; ks < 2; ++ks) {
            s16x8 af[MREP], bfr[4];
#pragma unroll
            for (int m = 0; m < MREP; ++m) {
                const int row = wm * (BM / 2) + m * 16 + r16;
                const int off = ((ks * 4 + g) * 16) ^ ((row & 7) << 4);
                af[m] = *(const s16x8*)((const char*)Ab + row * 128 + off);
            }
#pragma unroll
            for (int n = 0; n < 4; ++n) {
                const int row = wn * 64 + n * 16 + r16;
                const int off = ((ks * 4 + g) * 16) ^ ((row & 7) << 4);
                bfr[n] = *(const s16x8*)((const char*)Bb + row * 128 + off);
            }
#pragma unroll
            for (int m = 0; m < MREP; ++m)
#pragma unroll
                for (int n = 0; n < 4; ++n)
                    acc[m][n] = __builtin_amdgcn_mfma_f32_16x16x32_bf16(af[m], bfr[n], acc[m][n], 0, 0, 0);
        }
        asm volatile("s_waitcnt lgkmcnt(0)" ::: "memory");
        __builtin_amdgcn_s_barrier();
        asm volatile("" ::: "memory");
    }

    // epilogue: bias + relu + bf16 store.  D: col=lane&15, row=(lane>>4)*4+r
#pragma unroll
    for (int n = 0; n < 4; ++n) {
        const int col = colBase + wn * 64 + n * 16 + r16;
        const float bv = (col < biasN) ? bias[col] : 0.f;
#pragma unroll
        for (int m = 0; m < MREP; ++m) {
            const int rowB = rowBase + wm * (BM / 2) + m * 16 + g * 4;
#pragma unroll
            for (int r = 0; r < 4; ++r) {
                float v = acc[m][n][r] + bv;
                v = v > 0.f ? v : 0.f;
                C[(size_t)(rowB + r) * ldc + col] = f2bf(v);
            }
        }
    }
}

// ---------------------------------------------------------------------------
// GEMM3 + tail dot + final sigmoid:
//   tail[b] = relu(d2@W3 + b3) . Wl[1024:1224]
//   out[i*B + b] = sigmoid(zc[i][b] + tail[b] + bl)
// Block: 64 rows x 256 cols (full padded N), 4 waves side-by-side in N.
// ---------------------------------------------------------------------------
__global__ __launch_bounds__(256) void gemm3_final(
    const unsigned short* __restrict__ d2,   // M x 256 bf16
    const unsigned short* __restrict__ W3b,  // 256 x 256 bf16 (N x K)
    const float* __restrict__ b3,
    const float* __restrict__ Wl,            // 1224 floats
    const float* __restrict__ bl,
    const float* __restrict__ zc,            // 2 * B_ROWS
    float* __restrict__ out) {
    __shared__ unsigned short As[64 * 32];
    __shared__ unsigned short Bs[256 * 32];
    __shared__ float part[4][64];

    const int tid  = threadIdx.x;
    const int lane = tid & 63;
    const int wid  = tid >> 6;
    const int rowBase = blockIdx.x << 6;

    const int g   = lane >> 4;
    const int r16 = lane & 15;

    f32x4 acc[4][4];
#pragma unroll
    for (int m = 0; m < 4; ++m)
#pragma unroll
        for (int n = 0; n < 4; ++n)
            acc[m][n] = (f32x4){0.f, 0.f, 0.f, 0.f};

    for (int kt = 0; kt < 8; ++kt) {
        const int k0 = kt << 5;
        {
            const int ar = tid >> 2, ac = tid & 3;
            int4 v = *(const int4*)(d2 + (size_t)(rowBase + ar) * 256 + k0 + ac * 8);
            const int off = (ac * 16) ^ ((ar & 3) << 4);
            *(int4*)((char*)As + ar * 64 + off) = v;
        }
        {
            const int n = tid;
#pragma unroll
            for (int c = 0; c < 4; ++c) {
                int4 v = *(const int4*)(W3b + (size_t)n * 256 + k0 + c * 8);
                const int off = (c * 16) ^ ((n & 3) << 4);
                *(int4*)((char*)Bs + n * 64 + off) = v;
            }
        }
        __syncthreads();

        s16x8 af[4], bfr[4];
#pragma unroll
        for (int m = 0; m < 4; ++m) {
            const int row = m * 16 + r16;
            const int off = (g * 16) ^ ((row & 3) << 4);
            af[m] = *(const s16x8*)((const char*)As + row * 64 + off);
        }
#pragma unroll
        for (int n = 0; n < 4; ++n) {
            const int row = wid * 64 + n * 16 + r16;
            const int off = (g * 16) ^ ((row & 3) << 4);
            bfr[n] = *(const s16x8*)((const char*)Bs + row * 64 + off);
        }
#pragma unroll
        for (int m = 0; m < 4; ++m)
#pragma unroll
            for (int n = 0; n < 4; ++n)
                acc[m][n] = __builtin_amdgcn_mfma_f32_16x16x32_bf16(af[m], bfr[n], acc[m][n], 0, 0, 0);
        __syncthreads();
    }

    float wlv[4], b3v[4];
#pragma unroll
    for (int n = 0; n < 4; ++n) {
        const int col = wid * 64 + n * 16 + r16;
        wlv[n] = (col < 200) ? Wl[1024 + col] : 0.f;
        b3v[n] = (col < 200) ? b3[col] : 0.f;
    }
#pragma unroll
    for (int m = 0; m < 4; ++m) {
#pragma unroll
        for (int r = 0; r < 4; ++r) {
            float s = 0.f;
#pragma unroll
            for (int n = 0; n < 4; ++n) {
                float v = acc[m][n][r] + b3v[n];
                v = v > 0.f ? v : 0.f;
                s += v * wlv[n];
            }
            s += __shfl_xor(s, 1, 64);
            s += __shfl_xor(s, 2, 64);
            s += __shfl_xor(s, 4, 64);
            s += __shfl_xor(s, 8, 64);
            if (r16 == 0) part[wid][m * 16 + g * 4 + r] = s;
        }
    }
    __syncthreads();
    if (tid < 64) {
        const int row = rowBase + tid;
        const float t = part[0][tid] + part[1][tid] + part[2][tid] + part[3][tid];
        const float blv = bl[0];
        const float z0 = zc[row] + t + blv;
        const float z1 = zc[B_ROWS + row] + t + blv;
        out[row]          = 1.f / (1.f + expf(-z0));
        out[B_ROWS + row] = 1.f / (1.f + expf(-z1));
    }
}

// ---------------------------------------------------------------------------
extern "C" void kernel_launch(void* const* d_in, const int* in_sizes, int n_in,
                              void* d_out, int out_size, void* d_ws, size_t ws_size,
                              hipStream_t stream) {
    const float* x  = (const float*)d_in[0];
    const float* W1 = (const float*)d_in[3];
    const float* b1 = (const float*)d_in[4];
    const float* W2 = (const float*)d_in[5];
    const float* b2 = (const float*)d_in[6];
    const float* W3 = (const float*)d_in[7];
    const float* b3 = (const float*)d_in[8];
    const float* Wl = (const float*)d_in[9];
    const float* bl = (const float*)d_in[10];
    const float* cw = (const float*)d_in[11];
    const float* cb = (const float*)d_in[12];
    float* out = (float*)d_out;

    // workspace layout (bf16 = unsigned short)
    unsigned short* xb  = (unsigned short*)d_ws;          // 16384 x 1024
    unsigned short* d1  = xb + (size_t)16384 * 1024;      // 16384 x 512
    unsigned short* d2  = d1 + (size_t)16384 * 512;       // 16384 x 256
    unsigned short* W1b = d2 + (size_t)16384 * 256;       // 512 x 1024
    unsigned short* W2b = W1b + (size_t)512 * 1024;       // 256 x 512
    unsigned short* W3b = W2b + (size_t)256 * 512;        // 256 x 256
    float* zc = (float*)(W3b + (size_t)256 * 256);        // 2 x 16384

    // x convert + cross-net partial logits (4096 blocks) + weight transpose (176)
    prep<<<4096 + 176, 256, 0, stream>>>(x, xb, cw, cb, Wl, zc, W1, W2, W3, W1b, W2b, W3b);

    // d1 = relu(xb @ W1 + b1): M=16384, K=1024, ldc=512  (BM=64 -> 1024 blocks)
    gemm_bf16<64><<<1024, 256, 0, stream>>>(xb, W1b, b1, 500, d1, 1024, 512);

    // d2 = relu(d1 @ W2 + b2): K=512, ldc=256  (512 blocks)
    gemm_bf16<64><<<512, 256, 0, stream>>>(d1, W2b, b2, 200, d2, 512, 256);

    // tail + final sigmoid outputs
    gemm3_final<<<256, 256, 0, stream>>>(d2, W3b, b3, Wl, bl, zc, out);
}

// Round 4
// 83.825 us; speedup vs baseline: 1.3673x; 1.0992x over previous
//
#include <hip/hip_runtime.h>
#include <hip/hip_bf16.h>
#include <math.h>

#define B_ROWS 16384
#define DIM 1024

typedef __attribute__((ext_vector_type(8))) short s16x8;
typedef __attribute__((ext_vector_type(4))) short s16x4;
typedef __attribute__((ext_vector_type(4))) float f32x4;

static __device__ __forceinline__ unsigned short f2bf(float f) {
    union { float f; unsigned u; } v; v.f = f;
    unsigned r = v.u + 0x7FFF + ((v.u >> 16) & 1);  // RNE
    return (unsigned short)(r >> 16);
}
static __device__ __forceinline__ float bf2f(unsigned short h) {
    union { unsigned u; float f; } v; v.u = ((unsigned)h) << 16;
    return v.f;
}

// async global -> LDS, 16 bytes per lane; lds base wave-uniform, HW adds lane*16
static __device__ __forceinline__ void gload16(const unsigned short* g, unsigned short* l) {
    __builtin_amdgcn_global_load_lds(
        (const __attribute__((address_space(1))) unsigned int*)g,
        (__attribute__((address_space(3))) unsigned int*)l, 16, 0, 0);
}

// ---------------------------------------------------------------------------
// prep_w: weight transpose+convert+pad via 64x64 LDS tiles, coalesced both
// sides.  W1(1024x500)->W1b(512x1024 NxK), W2(500x200)->W2b(256x512),
// W3(200x200)->W3b(256x256).  Zero-padded.
// ---------------------------------------------------------------------------
__global__ __launch_bounds__(256) void prep_w(
    const float* __restrict__ W1, const float* __restrict__ W2,
    const float* __restrict__ W3,
    unsigned short* __restrict__ W1b, unsigned short* __restrict__ W2b,
    unsigned short* __restrict__ W3b) {
    __shared__ unsigned short tile[64][72];
    const int tid = threadIdx.x;
    const int w = blockIdx.x;
    const float* src; unsigned short* dst;
    int kt, nt, Ksrc, Nsrc, ldDst;
    if (w < 128)      { kt = w & 15;         nt = w >> 4;         src = W1; dst = W1b; Ksrc = 1024; Nsrc = 500; ldDst = 1024; }
    else if (w < 160) { kt = (w - 128) & 7;  nt = (w - 128) >> 3; src = W2; dst = W2b; Ksrc = 500;  Nsrc = 200; ldDst = 512;  }
    else              { kt = (w - 160) & 3;  nt = (w - 160) >> 2; src = W3; dst = W3b; Ksrc = 200;  Nsrc = 200; ldDst = 256;  }
    const int k0 = kt << 6, n0 = nt << 6;
    {
        const int r = tid >> 2, c0 = (tid & 3) << 4;
        const int kk = k0 + r;
#pragma unroll
        for (int i = 0; i < 16; ++i) {
            const int nn = n0 + c0 + i;
            const float v = (kk < Ksrc && nn < Nsrc) ? src[(size_t)kk * Nsrc + nn] : 0.f;
            tile[r][c0 + i] = f2bf(v);
        }
    }
    __syncthreads();
    {
        const int n = tid >> 2, kc = (tid & 3) << 4;
        unsigned short* o = dst + (size_t)(n0 + n) * ldDst + k0 + kc;
#pragma unroll
        for (int i = 0; i < 16; ++i) o[i] = tile[kc + i][n];
    }
}

// ---------------------------------------------------------------------------
// prep_x: per row — convert x->xb (bf16), and compute both cross-net partial
// logits zc[i][row] = emb3(i) . Wl[:1024] entirely in registers.
// cw/cb staged ONCE per block into LDS as interleaved bf16
// [layer][chunk(4 elems)][cw x4, cb x4]  (24 KB, lane-consecutive 16B reads).
// __launch_bounds__(256,2) lifts the VGPR cap so xv/e/wlv all stay live.
// Recurrence hoisted:  e = fma(e, xs*wv, bv + xv).
// ---------------------------------------------------------------------------
__global__ __launch_bounds__(256, 2) void prep_x(
    const float* __restrict__ x, unsigned short* __restrict__ xb,
    const float* __restrict__ cw, const float* __restrict__ cb,
    const float* __restrict__ Wl,
    float* __restrict__ zc) {
    __shared__ unsigned short swb[6 * 256 * 8];   // 24 KB
    const int tid  = threadIdx.x;
    const int lane = tid & 63;
    const int wid  = tid >> 6;

    // stage cw/cb -> LDS (bf16, interleaved); 6*256 chunks / 256 threads = 6 each
#pragma unroll
    for (int s0 = 0; s0 < 6; ++s0) {
        const int s = s0 * 256 + tid;
        const int l = s >> 8, ch = s & 255;
        float4 w4 = *(const float4*)(cw + (size_t)l * DIM + ch * 4);
        float4 b4 = *(const float4*)(cb + (size_t)l * DIM + ch * 4);
        s16x8 pk;
        pk[0] = (short)f2bf(w4.x); pk[1] = (short)f2bf(w4.y);
        pk[2] = (short)f2bf(w4.z); pk[3] = (short)f2bf(w4.w);
        pk[4] = (short)f2bf(b4.x); pk[5] = (short)f2bf(b4.y);
        pk[6] = (short)f2bf(b4.z); pk[7] = (short)f2bf(b4.w);
        *(s16x8*)(swb + (size_t)s * 8) = pk;
    }
    __syncthreads();

    const int row = (blockIdx.x << 2) + wid;
    const float* xr = x + (size_t)row * DIM;
    unsigned short* xo = xb + (size_t)row * DIM;

    float xv[16];
#pragma unroll
    for (int c = 0; c < 4; ++c)
        *(float4*)&xv[c * 4] = *(const float4*)(xr + c * 256 + lane * 4);

    // bf16 copy for GEMM1
#pragma unroll
    for (int c = 0; c < 4; ++c) {
        short4 h;
        h.x = (short)f2bf(xv[c * 4 + 0]); h.y = (short)f2bf(xv[c * 4 + 1]);
        h.z = (short)f2bf(xv[c * 4 + 2]); h.w = (short)f2bf(xv[c * 4 + 3]);
        *(short4*)(xo + c * 256 + lane * 4) = h;
    }

    float xs = 0.f;
#pragma unroll
    for (int t = 0; t < 16; ++t) xs += xv[t];
#pragma unroll
    for (int m = 1; m < 64; m <<= 1) xs += __shfl_xor(xs, m, 64);

    float wlv[16];
#pragma unroll
    for (int c = 0; c < 4; ++c)
        *(float4*)&wlv[c * 4] = *(const float4*)(Wl + c * 256 + lane * 4);

#pragma unroll
    for (int i = 0; i < 2; ++i) {
        float e[16];
#pragma unroll
        for (int t = 0; t < 16; ++t) e[t] = xv[t];
#pragma unroll
        for (int j = 0; j < 3; ++j) {
            const int l = i * 3 + j;
#pragma unroll
            for (int c = 0; c < 4; ++c) {
                s16x8 pk = *(const s16x8*)(swb + (size_t)((l << 8) + (c << 6) + lane) * 8);
#pragma unroll
                for (int q = 0; q < 4; ++q) {
                    const int t = c * 4 + q;
                    const float wv = bf2f((unsigned short)pk[q]);
                    const float bv = bf2f((unsigned short)pk[4 + q]);
                    e[t] = fmaf(e[t], xs * wv, bv + xv[t]);
                }
            }
        }
        float z = 0.f;
#pragma unroll
        for (int t = 0; t < 16; ++t) z += e[t] * wlv[t];
#pragma unroll
        for (int m = 1; m < 64; m <<= 1) z += __shfl_xor(z, m, 64);
        if (lane == 0) zc[(size_t)i * B_ROWS + row] = z;
    }
}

// ---------------------------------------------------------------------------
// bf16 GEMM + bias + ReLU, tile BM x 128, BK=64, 4 waves.
// global_load_lds dwordx4, pre-swizzled global source, linear LDS dest,
// XOR-swizzled ds_read_b128, double-buffered, counted vmcnt, raw s_barrier.
// ---------------------------------------------------------------------------
template <int ROWS>
static __device__ __forceinline__ void stage_tile(
    const unsigned short* __restrict__ src, int K, int rowBase, int kt,
    unsigned short* lds, int w, int lane) {
    const int r8   = lane >> 3;
    const int slot = lane & 7;
#pragma unroll
    for (int q = 0; q < ROWS / 32; ++q) {
        const int blk   = q * 4 + w;
        const int row   = blk * 8 + r8;
        const int chunk = slot ^ (row & 7);
        const unsigned short* g = src + (size_t)(rowBase + row) * K + kt * 64 + chunk * 8;
        gload16(g, lds + blk * 512);
    }
}

template <int BM>
__global__ __launch_bounds__(256) void gemm_bf16(
    const unsigned short* __restrict__ A,    // M x K bf16
    const unsigned short* __restrict__ Bw,   // ldc x K bf16 (N-major)
    const float* __restrict__ bias, int biasN,
    unsigned short* __restrict__ C,          // M x ldc bf16
    int K, int ldc) {
    constexpr int MREP = BM / 32;
    __shared__ unsigned short As[2][BM * 64];
    __shared__ unsigned short Bs[2][128 * 64];

    const int tid  = threadIdx.x;
    const int lane = tid & 63;
    const int wid  = tid >> 6;
    const int wm   = wid >> 1;
    const int wn   = wid & 1;
    const int g    = lane >> 4;
    const int r16  = lane & 15;

    const int cpx = gridDim.x >> 3;
    const int swz = (blockIdx.x & 7) * cpx + (blockIdx.x >> 3);
    const int nColTiles = ldc >> 7;
    const int rowBase = (swz / nColTiles) * BM;
    const int colBase = (swz % nColTiles) << 7;

    f32x4 acc[MREP][4];
#pragma unroll
    for (int m = 0; m < MREP; ++m)
#pragma unroll
        for (int n = 0; n < 4; ++n)
            acc[m][n] = (f32x4){0.f, 0.f, 0.f, 0.f};

    stage_tile<BM>(A, K, rowBase, 0, As[0], wid, lane);
    stage_tile<128>(Bw, K, colBase, 0, Bs[0], wid, lane);

    const int nK = K >> 6;
    for (int kt = 0; kt < nK; ++kt) {
        const int buf = kt & 1;
        if (kt + 1 < nK) {
            stage_tile<BM>(A, K, rowBase, kt + 1, As[buf ^ 1], wid, lane);
            stage_tile<128>(Bw, K, colBase, kt + 1, Bs[buf ^ 1], wid, lane);
            if constexpr (BM == 128)
                asm volatile("s_waitcnt vmcnt(8)" ::: "memory");
            else
                asm volatile("s_waitcnt vmcnt(6)" ::: "memory");
        } else {
            asm volatile("s_waitcnt vmcnt(0)" ::: "memory");
        }
        __builtin_amdgcn_s_barrier();
        asm volatile("" ::: "memory");

        const unsigned short* Ab = As[buf];
        const unsigned short* Bb = Bs[buf];
#pragma unroll
        for (int ks = 0; ks < 2; ++ks) {
            s16x8 af[MREP], bfr[4];
#pragma unroll
            for (int m = 0; m < MREP; ++m) {
                const int row = wm * (BM / 2) + m * 16 + r16;
                const int off = ((ks * 4 + g) * 16) ^ ((row & 7) << 4);
                af[m] = *(const s16x8*)((const char*)Ab + row * 128 + off);
            }
#pragma unroll
            for (int n = 0; n < 4; ++n) {
                const int row = wn * 64 + n * 16 + r16;
                const int off = ((ks * 4 + g) * 16) ^ ((row & 7) << 4);
                bfr[n] = *(const s16x8*)((const char*)Bb + row * 128 + off);
            }
#pragma unroll
            for (int m = 0; m < MREP; ++m)
#pragma unroll
                for (int n = 0; n < 4; ++n)
                    acc[m][n] = __builtin_amdgcn_mfma_f32_16x16x32_bf16(af[m], bfr[n], acc[m][n], 0, 0, 0);
        }
        asm volatile("s_waitcnt lgkmcnt(0)" ::: "memory");
        __builtin_amdgcn_s_barrier();
        asm volatile("" ::: "memory");
    }

#pragma unroll
    for (int n = 0; n < 4; ++n) {
        const int col = colBase + wn * 64 + n * 16 + r16;
        const float bv = (col < biasN) ? bias[col] : 0.f;
#pragma unroll
        for (int m = 0; m < MREP; ++m) {
            const int rowB = rowBase + wm * (BM / 2) + m * 16 + g * 4;
#pragma unroll
            for (int r = 0; r < 4; ++r) {
                float v = acc[m][n][r] + bv;
                v = v > 0.f ? v : 0.f;
                C[(size_t)(rowB + r) * ldc + col] = f2bf(v);
            }
        }
    }
}

// ---------------------------------------------------------------------------
// GEMM3 + tail dot + final sigmoid.
// ---------------------------------------------------------------------------
__global__ __launch_bounds__(256) void gemm3_final(
    const unsigned short* __restrict__ d2,   // M x 256 bf16
    const unsigned short* __restrict__ W3b,  // 256 x 256 bf16 (N x K)
    const float* __restrict__ b3,
    const float* __restrict__ Wl,            // 1224 floats
    const float* __restrict__ bl,
    const float* __restrict__ zc,            // 2 * B_ROWS
    float* __restrict__ out) {
    __shared__ unsigned short As[64 * 32];
    __shared__ unsigned short Bs[256 * 32];
    __shared__ float part[4][64];

    const int tid  = threadIdx.x;
    const int lane = tid & 63;
    const int wid  = tid >> 6;
    const int rowBase = blockIdx.x << 6;

    const int g   = lane >> 4;
    const int r16 = lane & 15;

    f32x4 acc[4][4];
#pragma unroll
    for (int m = 0; m < 4; ++m)
#pragma unroll
        for (int n = 0; n < 4; ++n)
            acc[m][n] = (f32x4){0.f, 0.f, 0.f, 0.f};

    for (int kt = 0; kt < 8; ++kt) {
        const int k0 = kt << 5;
        {
            const int ar = tid >> 2, ac = tid & 3;
            int4 v = *(const int4*)(d2 + (size_t)(rowBase + ar) * 256 + k0 + ac * 8);
            const int off = (ac * 16) ^ ((ar & 3) << 4);
            *(int4*)((char*)As + ar * 64 + off) = v;
        }
        {
            const int n = tid;
#pragma unroll
            for (int c = 0; c < 4; ++c) {
                int4 v = *(const int4*)(W3b + (size_t)n * 256 + k0 + c * 8);
                const int off = (c * 16) ^ ((n & 3) << 4);
                *(int4*)((char*)Bs + n * 64 + off) = v;
            }
        }
        __syncthreads();

        s16x8 af[4], bfr[4];
#pragma unroll
        for (int m = 0; m < 4; ++m) {
            const int row = m * 16 + r16;
            const int off = (g * 16) ^ ((row & 3) << 4);
            af[m] = *(const s16x8*)((const char*)As + row * 64 + off);
        }
#pragma unroll
        for (int n = 0; n < 4; ++n) {
            const int row = wid * 64 + n * 16 + r16;
            const int off = (g * 16) ^ ((row & 3) << 4);
            bfr[n] = *(const s16x8*)((const char*)Bs + row * 64 + off);
        }
#pragma unroll
        for (int m = 0; m < 4; ++m)
#pragma unroll
            for (int n = 0; n < 4; ++n)
                acc[m][n] = __builtin_amdgcn_mfma_f32_16x16x32_bf16(af[m], bfr[n], acc[m][n], 0, 0, 0);
        __syncthreads();
    }

    float wlv[4], b3v[4];
#pragma unroll
    for (int n = 0; n < 4; ++n) {
        const int col = wid * 64 + n * 16 + r16;
        wlv[n] = (col < 200) ? Wl[1024 + col] : 0.f;
        b3v[n] = (col < 200) ? b3[col] : 0.f;
    }
#pragma unroll
    for (int m = 0; m < 4; ++m) {
#pragma unroll
        for (int r = 0; r < 4; ++r) {
            float s = 0.f;
#pragma unroll
            for (int n = 0; n < 4; ++n) {
                float v = acc[m][n][r] + b3v[n];
                v = v > 0.f ? v : 0.f;
                s += v * wlv[n];
            }
            s += __shfl_xor(s, 1, 64);
            s += __shfl_xor(s, 2, 64);
            s += __shfl_xor(s, 4, 64);
            s += __shfl_xor(s, 8, 64);
            if (r16 == 0) part[wid][m * 16 + g * 4 + r] = s;
        }
    }
    __syncthreads();
    if (tid < 64) {
        const int row = rowBase + tid;
        const float t = part[0][tid] + part[1][tid] + part[2][tid] + part[3][tid];
        const float blv = bl[0];
        const float z0 = zc[row] + t + blv;
        const float z1 = zc[B_ROWS + row] + t + blv;
        out[row]          = 1.f / (1.f + expf(-z0));
        out[B_ROWS + row] = 1.f / (1.f + expf(-z1));
    }
}

// ---------------------------------------------------------------------------
extern "C" void kernel_launch(void* const* d_in, const int* in_sizes, int n_in,
                              void* d_out, int out_size, void* d_ws, size_t ws_size,
                              hipStream_t stream) {
    const float* x  = (const float*)d_in[0];
    const float* W1 = (const float*)d_in[3];
    const float* b1 = (const float*)d_in[4];
    const float* W2 = (const float*)d_in[5];
    const float* b2 = (const float*)d_in[6];
    const float* W3 = (const float*)d_in[7];
    const float* b3 = (const float*)d_in[8];
    const float* Wl = (const float*)d_in[9];
    const float* bl = (const float*)d_in[10];
    const float* cw = (const float*)d_in[11];
    const float* cb = (const float*)d_in[12];
    float* out = (float*)d_out;

    unsigned short* xb  = (unsigned short*)d_ws;          // 16384 x 1024
    unsigned short* d1  = xb + (size_t)16384 * 1024;      // 16384 x 512
    unsigned short* d2  = d1 + (size_t)16384 * 512;       // 16384 x 256
    unsigned short* W1b = d2 + (size_t)16384 * 256;       // 512 x 1024
    unsigned short* W2b = W1b + (size_t)512 * 1024;       // 256 x 512
    unsigned short* W3b = W2b + (size_t)256 * 512;        // 256 x 256
    float* zc = (float*)(W3b + (size_t)256 * 256);        // 2 x 16384

    prep_w<<<176, 256, 0, stream>>>(W1, W2, W3, W1b, W2b, W3b);
    prep_x<<<4096, 256, 0, stream>>>(x, xb, cw, cb, Wl, zc);

    // d1 = relu(xb @ W1 + b1): M=16384, K=1024, ldc=512
    gemm_bf16<64><<<1024, 256, 0, stream>>>(xb, W1b, b1, 500, d1, 1024, 512);

    // d2 = relu(d1 @ W2 + b2): K=512, ldc=256
    gemm_bf16<64><<<512, 256, 0, stream>>>(d1, W2b, b2, 200, d2, 512, 256);

    // tail + final sigmoid
    gemm3_final<<<256, 256, 0, stream>>>(d2, W3b, b3, Wl, bl, zc, out);
}

// Round 5
// 80.287 us; speedup vs baseline: 1.4275x; 1.0441x over previous
//
#include <hip/hip_runtime.h>
#include <hip/hip_bf16.h>
#include <math.h>

#define B_ROWS 16384
#define DIM 1024

typedef __attribute__((ext_vector_type(8))) short s16x8;
typedef __attribute__((ext_vector_type(4))) short s16x4;
typedef __attribute__((ext_vector_type(4))) float f32x4;

static __device__ __forceinline__ unsigned short f2bf(float f) {
    union { float f; unsigned u; } v; v.f = f;
    unsigned r = v.u + 0x7FFF + ((v.u >> 16) & 1);  // RNE
    return (unsigned short)(r >> 16);
}
static __device__ __forceinline__ float bf2f(unsigned short h) {
    union { unsigned u; float f; } v; v.u = ((unsigned)h) << 16;
    return v.f;
}

// async global -> LDS, 16 bytes per lane; lds base wave-uniform, HW adds lane*16
static __device__ __forceinline__ void gload16(const unsigned short* g, unsigned short* l) {
    __builtin_amdgcn_global_load_lds(
        (const __attribute__((address_space(1))) unsigned int*)g,
        (__attribute__((address_space(3))) unsigned int*)l, 16, 0, 0);
}

// ---------------------------------------------------------------------------
// prep_w: weight transpose+convert+pad via 64x64 LDS tiles, coalesced both
// sides.  W1(1024x500)->W1b(512x1024 NxK), W2(500x200)->W2b(256x512),
// W3(200x200)->W3b(256x256).  Zero-padded.
// ---------------------------------------------------------------------------
__global__ __launch_bounds__(256) void prep_w(
    const float* __restrict__ W1, const float* __restrict__ W2,
    const float* __restrict__ W3,
    unsigned short* __restrict__ W1b, unsigned short* __restrict__ W2b,
    unsigned short* __restrict__ W3b) {
    __shared__ unsigned short tile[64][72];
    const int tid = threadIdx.x;
    const int w = blockIdx.x;
    const float* src; unsigned short* dst;
    int kt, nt, Ksrc, Nsrc, ldDst;
    if (w < 128)      { kt = w & 15;         nt = w >> 4;         src = W1; dst = W1b; Ksrc = 1024; Nsrc = 500; ldDst = 1024; }
    else if (w < 160) { kt = (w - 128) & 7;  nt = (w - 128) >> 3; src = W2; dst = W2b; Ksrc = 500;  Nsrc = 200; ldDst = 512;  }
    else              { kt = (w - 160) & 3;  nt = (w - 160) >> 2; src = W3; dst = W3b; Ksrc = 200;  Nsrc = 200; ldDst = 256;  }
    const int k0 = kt << 6, n0 = nt << 6;
    {
        const int r = tid >> 2, c0 = (tid & 3) << 4;
        const int kk = k0 + r;
#pragma unroll
        for (int i = 0; i < 16; ++i) {
            const int nn = n0 + c0 + i;
            const float v = (kk < Ksrc && nn < Nsrc) ? src[(size_t)kk * Nsrc + nn] : 0.f;
            tile[r][c0 + i] = f2bf(v);
        }
    }
    __syncthreads();
    {
        const int n = tid >> 2, kc = (tid & 3) << 4;
        unsigned short* o = dst + (size_t)(n0 + n) * ldDst + k0 + kc;
#pragma unroll
        for (int i = 0; i < 16; ++i) o[i] = tile[kc + i][n];
    }
}

// ---------------------------------------------------------------------------
// prep_x: 2 rows per wave (8 per block) — convert x->xb (bf16) and compute
// both cross-net partial logits zc[i][row] = emb3(i) . Wl[:1024] in f32.
// cw/cb staged once per block into LDS as interleaved bf16 (24 KB); one LDS
// read feeds BOTH rows, halving per-row LDS traffic vs 1-row/wave.
// ---------------------------------------------------------------------------
__global__ __launch_bounds__(256, 2) void prep_x(
    const float* __restrict__ x, unsigned short* __restrict__ xb,
    const float* __restrict__ cw, const float* __restrict__ cb,
    const float* __restrict__ Wl,
    float* __restrict__ zc) {
    __shared__ unsigned short swb[6 * 256 * 8];   // 24 KB
    const int tid  = threadIdx.x;
    const int lane = tid & 63;
    const int wid  = tid >> 6;

    // stage cw/cb -> LDS (bf16, interleaved [layer][chunk][cw x4, cb x4])
#pragma unroll
    for (int s0 = 0; s0 < 6; ++s0) {
        const int s = s0 * 256 + tid;
        const int l = s >> 8, ch = s & 255;
        float4 w4 = *(const float4*)(cw + (size_t)l * DIM + ch * 4);
        float4 b4 = *(const float4*)(cb + (size_t)l * DIM + ch * 4);
        s16x8 pk;
        pk[0] = (short)f2bf(w4.x); pk[1] = (short)f2bf(w4.y);
        pk[2] = (short)f2bf(w4.z); pk[3] = (short)f2bf(w4.w);
        pk[4] = (short)f2bf(b4.x); pk[5] = (short)f2bf(b4.y);
        pk[6] = (short)f2bf(b4.z); pk[7] = (short)f2bf(b4.w);
        *(s16x8*)(swb + (size_t)s * 8) = pk;
    }
    __syncthreads();

    const int r0 = (blockIdx.x << 3) + (wid << 1);   // 2 rows per wave

    float xv[2][16];
#pragma unroll
    for (int rr = 0; rr < 2; ++rr) {
        const float* xr = x + (size_t)(r0 + rr) * DIM;
#pragma unroll
        for (int c = 0; c < 4; ++c)
            *(float4*)&xv[rr][c * 4] = *(const float4*)(xr + c * 256 + lane * 4);
    }

    // bf16 copies for GEMM1
#pragma unroll
    for (int rr = 0; rr < 2; ++rr) {
        unsigned short* xo = xb + (size_t)(r0 + rr) * DIM;
#pragma unroll
        for (int c = 0; c < 4; ++c) {
            short4 h;
            h.x = (short)f2bf(xv[rr][c * 4 + 0]); h.y = (short)f2bf(xv[rr][c * 4 + 1]);
            h.z = (short)f2bf(xv[rr][c * 4 + 2]); h.w = (short)f2bf(xv[rr][c * 4 + 3]);
            *(short4*)(xo + c * 256 + lane * 4) = h;
        }
    }

    float xs0 = 0.f, xs1 = 0.f;
#pragma unroll
    for (int t = 0; t < 16; ++t) { xs0 += xv[0][t]; xs1 += xv[1][t]; }
#pragma unroll
    for (int m = 1; m < 64; m <<= 1) {
        xs0 += __shfl_xor(xs0, m, 64);
        xs1 += __shfl_xor(xs1, m, 64);
    }

    float wlv[16];
#pragma unroll
    for (int c = 0; c < 4; ++c)
        *(float4*)&wlv[c * 4] = *(const float4*)(Wl + c * 256 + lane * 4);

#pragma unroll
    for (int i = 0; i < 2; ++i) {
        float e0[16], e1[16];
#pragma unroll
        for (int t = 0; t < 16; ++t) { e0[t] = xv[0][t]; e1[t] = xv[1][t]; }
#pragma unroll
        for (int j = 0; j < 3; ++j) {
            const int l = i * 3 + j;
#pragma unroll
            for (int c = 0; c < 4; ++c) {
                s16x8 pk = *(const s16x8*)(swb + (size_t)((l << 8) + (c << 6) + lane) * 8);
#pragma unroll
                for (int q = 0; q < 4; ++q) {
                    const int t = c * 4 + q;
                    const float wv = bf2f((unsigned short)pk[q]);
                    const float bv = bf2f((unsigned short)pk[4 + q]);
                    e0[t] = fmaf(e0[t], xs0 * wv, bv + xv[0][t]);
                    e1[t] = fmaf(e1[t], xs1 * wv, bv + xv[1][t]);
                }
            }
        }
        float z0 = 0.f, z1 = 0.f;
#pragma unroll
        for (int t = 0; t < 16; ++t) { z0 += e0[t] * wlv[t]; z1 += e1[t] * wlv[t]; }
#pragma unroll
        for (int m = 1; m < 64; m <<= 1) {
            z0 += __shfl_xor(z0, m, 64);
            z1 += __shfl_xor(z1, m, 64);
        }
        if (lane == 0) {
            zc[(size_t)i * B_ROWS + r0]     = z0;
            zc[(size_t)i * B_ROWS + r0 + 1] = z1;
        }
    }
}

// ---------------------------------------------------------------------------
// stage_tile: global_load_lds dwordx4 with pre-swizzled global source (linear
// LDS dest).  LDS logical layout: row-major [ROWS][64] bf16 (128B/row), with
// 16B chunk c holding global k-chunk (c ^ (row&7)).
// ---------------------------------------------------------------------------
template <int ROWS>
static __device__ __forceinline__ void stage_tile(
    const unsigned short* __restrict__ src, int K, int rowBase, int kt,
    unsigned short* lds, int w, int lane) {
    const int r8   = lane >> 3;
    const int slot = lane & 7;
#pragma unroll
    for (int q = 0; q < ROWS / 32; ++q) {
        const int blk   = q * 4 + w;
        const int row   = blk * 8 + r8;
        const int chunk = slot ^ (row & 7);
        const unsigned short* g = src + (size_t)(rowBase + row) * K + kt * 64 + chunk * 8;
        gload16(g, lds + blk * 512);
    }
}

// ---------------------------------------------------------------------------
// bf16 GEMM1 + bias + ReLU, tile 64 x 128, BK=64, 4 waves (2x2).
// Double-buffered, counted vmcnt, raw s_barrier, XOR-swizzled ds_read_b128.
// ---------------------------------------------------------------------------
template <int BM>
__global__ __launch_bounds__(256) void gemm_bf16(
    const unsigned short* __restrict__ A,    // M x K bf16
    const unsigned short* __restrict__ Bw,   // ldc x K bf16 (N-major)
    const float* __restrict__ bias, int biasN,
    unsigned short* __restrict__ C,          // M x ldc bf16
    int K, int ldc) {
    constexpr int MREP = BM / 32;
    __shared__ unsigned short As[2][BM * 64];
    __shared__ unsigned short Bs[2][128 * 64];

    const int tid  = threadIdx.x;
    const int lane = tid & 63;
    const int wid  = tid >> 6;
    const int wm   = wid >> 1;
    const int wn   = wid & 1;
    const int g    = lane >> 4;
    const int r16  = lane & 15;

    const int cpx = gridDim.x >> 3;
    const int swz = (blockIdx.x & 7) * cpx + (blockIdx.x >> 3);
    const int nColTiles = ldc >> 7;
    const int rowBase = (swz / nColTiles) * BM;
    const int colBase = (swz % nColTiles) << 7;

    f32x4 acc[MREP][4];
#pragma unroll
    for (int m = 0; m < MREP; ++m)
#pragma unroll
        for (int n = 0; n < 4; ++n)
            acc[m][n] = (f32x4){0.f, 0.f, 0.f, 0.f};

    stage_tile<BM>(A, K, rowBase, 0, As[0], wid, lane);
    stage_tile<128>(Bw, K, colBase, 0, Bs[0], wid, lane);

    const int nK = K >> 6;
    for (int kt = 0; kt < nK; ++kt) {
        const int buf = kt & 1;
        if (kt + 1 < nK) {
            stage_tile<BM>(A, K, rowBase, kt + 1, As[buf ^ 1], wid, lane);
            stage_tile<128>(Bw, K, colBase, kt + 1, Bs[buf ^ 1], wid, lane);
            if constexpr (BM == 128)
                asm volatile("s_waitcnt vmcnt(8)" ::: "memory");
            else
                asm volatile("s_waitcnt vmcnt(6)" ::: "memory");
        } else {
            asm volatile("s_waitcnt vmcnt(0)" ::: "memory");
        }
        __builtin_amdgcn_s_barrier();
        asm volatile("" ::: "memory");

        const unsigned short* Ab = As[buf];
        const unsigned short* Bb = Bs[buf];
#pragma unroll
        for (int ks = 0; ks < 2; ++ks) {
            s16x8 af[MREP], bfr[4];
#pragma unroll
            for (int m = 0; m < MREP; ++m) {
                const int row = wm * (BM / 2) + m * 16 + r16;
                const int off = ((ks * 4 + g) * 16) ^ ((row & 7) << 4);
                af[m] = *(const s16x8*)((const char*)Ab + row * 128 + off);
            }
#pragma unroll
            for (int n = 0; n < 4; ++n) {
                const int row = wn * 64 + n * 16 + r16;
                const int off = ((ks * 4 + g) * 16) ^ ((row & 7) << 4);
                bfr[n] = *(const s16x8*)((const char*)Bb + row * 128 + off);
            }
#pragma unroll
            for (int m = 0; m < MREP; ++m)
#pragma unroll
                for (int n = 0; n < 4; ++n)
                    acc[m][n] = __builtin_amdgcn_mfma_f32_16x16x32_bf16(af[m], bfr[n], acc[m][n], 0, 0, 0);
        }
        asm volatile("s_waitcnt lgkmcnt(0)" ::: "memory");
        __builtin_amdgcn_s_barrier();
        asm volatile("" ::: "memory");
    }

#pragma unroll
    for (int n = 0; n < 4; ++n) {
        const int col = colBase + wn * 64 + n * 16 + r16;
        const float bv = (col < biasN) ? bias[col] : 0.f;
#pragma unroll
        for (int m = 0; m < MREP; ++m) {
            const int rowB = rowBase + wm * (BM / 2) + m * 16 + g * 4;
#pragma unroll
            for (int r = 0; r < 4; ++r) {
                float v = acc[m][n][r] + bv;
                v = v > 0.f ? v : 0.f;
                C[(size_t)(rowB + r) * ldc + col] = f2bf(v);
            }
        }
    }
}

// ---------------------------------------------------------------------------
// tail_fused: per 64-row block —
//   phase 1: P = relu(d1[64x512] @ W2b^T + b2)  (64x256 bf16, kept in LDS)
//   phase 2: acc2 = P @ W3b^T
//   epilogue: tail = relu(acc2 + b3) . Wl[1024:], out = sigmoid(zc+tail+bl)
// d2 never touches global memory.  LDS: As 16K + Bs 64K + P 32K + part 1K.
// ---------------------------------------------------------------------------
__global__ __launch_bounds__(256) void tail_fused(
    const unsigned short* __restrict__ d1,   // 16384 x 512 bf16
    const unsigned short* __restrict__ W2b,  // 256 x 512 bf16 (N x K)
    const float* __restrict__ b2,
    const unsigned short* __restrict__ W3b,  // 256 x 256 bf16 (N x K)
    const float* __restrict__ b3,
    const float* __restrict__ Wl,            // 1224 floats
    const float* __restrict__ bl,
    const float* __restrict__ zc,            // 2 * B_ROWS
    float* __restrict__ out) {
    __shared__ unsigned short As[2][64 * 64];
    __shared__ unsigned short Bs[2][256 * 64];
    __shared__ unsigned short P[64 * 256];
    __shared__ float part[4][64];

    const int tid  = threadIdx.x;
    const int lane = tid & 63;
    const int wid  = tid >> 6;
    const int g    = lane >> 4;
    const int r16  = lane & 15;
    const int rowBase = blockIdx.x << 6;

    f32x4 acc[4][4];
#pragma unroll
    for (int m = 0; m < 4; ++m)
#pragma unroll
        for (int n = 0; n < 4; ++n)
            acc[m][n] = (f32x4){0.f, 0.f, 0.f, 0.f};

    // ---- phase 1: 64x512 @ W2b (256x512) -> acc (waves split 256 cols) ----
    stage_tile<64>(d1, 512, rowBase, 0, As[0], wid, lane);
    stage_tile<256>(W2b, 512, 0, 0, Bs[0], wid, lane);

    for (int kt = 0; kt < 8; ++kt) {
        const int buf = kt & 1;
        if (kt + 1 < 8) {
            stage_tile<64>(d1, 512, rowBase, kt + 1, As[buf ^ 1], wid, lane);
            stage_tile<256>(W2b, 512, 0, kt + 1, Bs[buf ^ 1], wid, lane);
            asm volatile("s_waitcnt vmcnt(10)" ::: "memory");
        } else {
            asm volatile("s_waitcnt vmcnt(0)" ::: "memory");
        }
        __builtin_amdgcn_s_barrier();
        asm volatile("" ::: "memory");

        const unsigned short* Ab = As[buf];
        const unsigned short* Bb = Bs[buf];
#pragma unroll
        for (int ks = 0; ks < 2; ++ks) {
            s16x8 af[4], bfr[4];
#pragma unroll
            for (int m = 0; m < 4; ++m) {
                const int row = m * 16 + r16;
                const int off = ((ks * 4 + g) * 16) ^ ((row & 7) << 4);
                af[m] = *(const s16x8*)((const char*)Ab + row * 128 + off);
            }
#pragma unroll
            for (int n = 0; n < 4; ++n) {
                const int row = wid * 64 + n * 16 + r16;
                const int off = ((ks * 4 + g) * 16) ^ ((row & 7) << 4);
                bfr[n] = *(const s16x8*)((const char*)Bb + row * 128 + off);
            }
#pragma unroll
            for (int m = 0; m < 4; ++m)
#pragma unroll
                for (int n = 0; n < 4; ++n)
                    acc[m][n] = __builtin_amdgcn_mfma_f32_16x16x32_bf16(af[m], bfr[n], acc[m][n], 0, 0, 0);
        }
        asm volatile("s_waitcnt lgkmcnt(0)" ::: "memory");
        __builtin_amdgcn_s_barrier();
        asm volatile("" ::: "memory");
    }

    // ---- phase-1 epilogue: bias + relu + bf16 -> P (XOR-swizzled) ----
#pragma unroll
    for (int n = 0; n < 4; ++n) {
        const int col = wid * 64 + n * 16 + r16;
        const float bv = (col < 200) ? b2[col] : 0.f;
#pragma unroll
        for (int m = 0; m < 4; ++m) {
#pragma unroll
            for (int r = 0; r < 4; ++r) {
                const int row = m * 16 + g * 4 + r;
                float v = acc[m][n][r] + bv;
                v = v > 0.f ? v : 0.f;
                const int byte = row * 512 + ((col * 2) ^ ((row & 7) << 4));
                *(unsigned short*)((char*)P + byte) = f2bf(v);
            }
        }
    }

    // ---- phase 2: P (64x256) @ W3b (256x256) ----
    stage_tile<256>(W3b, 256, 0, 0, Bs[0], wid, lane);
    asm volatile("s_waitcnt lgkmcnt(0)" ::: "memory");  // P writes visible
    __builtin_amdgcn_s_barrier();
    asm volatile("" ::: "memory");

    f32x4 acc2[4][4];
#pragma unroll
    for (int m = 0; m < 4; ++m)
#pragma unroll
        for (int n = 0; n < 4; ++n)
            acc2[m][n] = (f32x4){0.f, 0.f, 0.f, 0.f};

    for (int kt = 0; kt < 4; ++kt) {
        const int buf = kt & 1;
        if (kt + 1 < 4) {
            stage_tile<256>(W3b, 256, 0, kt + 1, Bs[buf ^ 1], wid, lane);
            asm volatile("s_waitcnt vmcnt(8)" ::: "memory");
        } else {
            asm volatile("s_waitcnt vmcnt(0)" ::: "memory");
        }
        __builtin_amdgcn_s_barrier();
        asm volatile("" ::: "memory");

        const unsigned short* Bb = Bs[buf];
#pragma unroll
        for (int ks = 0; ks < 2; ++ks) {
            s16x8 af[4], bfr[4];
#pragma unroll
            for (int m = 0; m < 4; ++m) {
                const int row = m * 16 + r16;
                const int byte = row * 512 + ((kt * 128 + (ks * 4 + g) * 16) ^ ((row & 7) << 4));
                af[m] = *(const s16x8*)((const char*)P + byte);
            }
#pragma unroll
            for (int n = 0; n < 4; ++n) {
                const int row = wid * 64 + n * 16 + r16;
                const int off = ((ks * 4 + g) * 16) ^ ((row & 7) << 4);
                bfr[n] = *(const s16x8*)((const char*)Bb + row * 128 + off);
            }
#pragma unroll
            for (int m = 0; m < 4; ++m)
#pragma unroll
                for (int n = 0; n < 4; ++n)
                    acc2[m][n] = __builtin_amdgcn_mfma_f32_16x16x32_bf16(af[m], bfr[n], acc2[m][n], 0, 0, 0);
        }
        asm volatile("s_waitcnt lgkmcnt(0)" ::: "memory");
        __builtin_amdgcn_s_barrier();
        asm volatile("" ::: "memory");
    }

    // ---- tail dot + sigmoid ----
    float wlv[4], b3v[4];
#pragma unroll
    for (int n = 0; n < 4; ++n) {
        const int col = wid * 64 + n * 16 + r16;
        wlv[n] = (col < 200) ? Wl[1024 + col] : 0.f;
        b3v[n] = (col < 200) ? b3[col] : 0.f;
    }
#pragma unroll
    for (int m = 0; m < 4; ++m) {
#pragma unroll
        for (int r = 0; r < 4; ++r) {
            float s = 0.f;
#pragma unroll
            for (int n = 0; n < 4; ++n) {
                float v = acc2[m][n][r] + b3v[n];
                v = v > 0.f ? v : 0.f;
                s += v * wlv[n];
            }
            s += __shfl_xor(s, 1, 64);
            s += __shfl_xor(s, 2, 64);
            s += __shfl_xor(s, 4, 64);
            s += __shfl_xor(s, 8, 64);
            if (r16 == 0) part[wid][m * 16 + g * 4 + r] = s;
        }
    }
    __syncthreads();
    if (tid < 64) {
        const int row = rowBase + tid;
        const float t = part[0][tid] + part[1][tid] + part[2][tid] + part[3][tid];
        const float blv = bl[0];
        const float z0 = zc[row] + t + blv;
        const float z1 = zc[B_ROWS + row] + t + blv;
        out[row]          = 1.f / (1.f + expf(-z0));
        out[B_ROWS + row] = 1.f / (1.f + expf(-z1));
    }
}

// ---------------------------------------------------------------------------
extern "C" void kernel_launch(void* const* d_in, const int* in_sizes, int n_in,
                              void* d_out, int out_size, void* d_ws, size_t ws_size,
                              hipStream_t stream) {
    const float* x  = (const float*)d_in[0];
    const float* W1 = (const float*)d_in[3];
    const float* b1 = (const float*)d_in[4];
    const float* W2 = (const float*)d_in[5];
    const float* b2 = (const float*)d_in[6];
    const float* W3 = (const float*)d_in[7];
    const float* b3 = (const float*)d_in[8];
    const float* Wl = (const float*)d_in[9];
    const float* bl = (const float*)d_in[10];
    const float* cw = (const float*)d_in[11];
    const float* cb = (const float*)d_in[12];
    float* out = (float*)d_out;

    unsigned short* xb  = (unsigned short*)d_ws;          // 16384 x 1024
    unsigned short* d1  = xb + (size_t)16384 * 1024;      // 16384 x 512
    unsigned short* W1b = d1 + (size_t)16384 * 512;       // 512 x 1024
    unsigned short* W2b = W1b + (size_t)512 * 1024;       // 256 x 512
    unsigned short* W3b = W2b + (size_t)256 * 512;        // 256 x 256
    float* zc = (float*)(W3b + (size_t)256 * 256);        // 2 x 16384

    prep_w<<<176, 256, 0, stream>>>(W1, W2, W3, W1b, W2b, W3b);
    prep_x<<<2048, 256, 0, stream>>>(x, xb, cw, cb, Wl, zc);

    // d1 = relu(xb @ W1 + b1): M=16384, K=1024, ldc=512
    gemm_bf16<64><<<1024, 256, 0, stream>>>(xb, W1b, b1, 500, d1, 1024, 512);

    // d2/d3/tail/sigmoid fused — d2 never hits memory
    tail_fused<<<256, 256, 0, stream>>>(d1, W2b, b2, W3b, b3, Wl, bl, zc, out);
}

// Round 6
// 64.337 us; speedup vs baseline: 1.7814x; 1.2479x over previous
//
#include <hip/hip_runtime.h>
#include <hip/hip_bf16.h>
#include <math.h>

#define B_ROWS 16384
#define DIM 1024

typedef __attribute__((ext_vector_type(8))) short s16x8;
typedef __attribute__((ext_vector_type(4))) float f32x4;

static __device__ __forceinline__ unsigned short f2bf(float f) {
    union { float f; unsigned u; } v; v.f = f;
    unsigned r = v.u + 0x7FFF + ((v.u >> 16) & 1);  // RNE
    return (unsigned short)(r >> 16);
}

// async global -> LDS, 16 bytes per lane; lds base wave-uniform, HW adds lane*16
static __device__ __forceinline__ void gload16(const unsigned short* g, unsigned short* l) {
    __builtin_amdgcn_global_load_lds(
        (const __attribute__((address_space(1))) unsigned int*)g,
        (__attribute__((address_space(3))) unsigned int*)l, 16, 0, 0);
}

// ---------------------------------------------------------------------------
// prep (one kernel, 4274 blocks):
//  [0,4096):  x f32 -> xb bf16 streaming convert (coalesced float4/short4)
//  [4096,4272): weight transpose+convert+pad via 64x64 LDS tiles.
//     W1 rows >=500 are NOT written here (owned by block 4272).
//  4272: cross-net P-vectors into W1b spare rows (GEMM columns):
//     500:P3_0 501:P2_0 502:P1_0 503:P3_1 504:P2_1 505:P1_1 506:Wl 507:ones
//     (P3=w1*w2*w3*wl, P2=w2*w3*wl, P1=w3*wl per element k; rows 508-511 = 0)
//  4273: cross-net scalar constants czz[6] = {C2_0,C1_0,C0_0,C2_1,C1_1,C0_1}
//     C2=sum(w2*w3*b1*wl), C1=sum(w3*b2*wl), C0=sum(b3*wl)
// Cross-net closed form (exact algebra):
//   z_i = s^3(x.P3_i)+s^2(x.P2_i)+s(x.P1_i)+(x.Wl)+s^2 C2_i+s C1_i+C0_i
// ---------------------------------------------------------------------------
__global__ __launch_bounds__(256) void prep(
    const float* __restrict__ x, unsigned short* __restrict__ xb,
    const float* __restrict__ W1, const float* __restrict__ W2,
    const float* __restrict__ W3,
    const float* __restrict__ cw, const float* __restrict__ cb,
    const float* __restrict__ Wl,
    unsigned short* __restrict__ W1b, unsigned short* __restrict__ W2b,
    unsigned short* __restrict__ W3b,
    float* __restrict__ czz) {
    __shared__ unsigned short tile[64][72];
    __shared__ float red[4][6];
    const int tid = threadIdx.x;
    const int blk = blockIdx.x;

    if (blk < 4096) {
        // ---- x convert: 4096 f32 per block ----
        const float* src = x + (size_t)blk * 4096;
        unsigned short* dst = xb + (size_t)blk * 4096;
#pragma unroll
        for (int r = 0; r < 4; ++r) {
            float4 f = *(const float4*)(src + r * 1024 + tid * 4);
            short4 h;
            h.x = (short)f2bf(f.x); h.y = (short)f2bf(f.y);
            h.z = (short)f2bf(f.z); h.w = (short)f2bf(f.w);
            *(short4*)(dst + r * 1024 + tid * 4) = h;
        }
    } else if (blk < 4272) {
        // ---- weight transpose tile ----
        const int w = blk - 4096;
        const float* src; unsigned short* dst;
        int kt, nt, Ksrc, Nsrc, ldDst;
        bool skipHi = false;
        if (w < 128)      { kt = w & 15;         nt = w >> 4;         src = W1; dst = W1b; Ksrc = 1024; Nsrc = 500; ldDst = 1024; skipHi = true; }
        else if (w < 160) { kt = (w - 128) & 7;  nt = (w - 128) >> 3; src = W2; dst = W2b; Ksrc = 500;  Nsrc = 200; ldDst = 512;  }
        else              { kt = (w - 160) & 3;  nt = (w - 160) >> 2; src = W3; dst = W3b; Ksrc = 200;  Nsrc = 200; ldDst = 256;  }
        const int k0 = kt << 6, n0 = nt << 6;
        {
            const int r = tid >> 2, c0 = (tid & 3) << 4;
            const int kk = k0 + r;
#pragma unroll
            for (int i = 0; i < 16; ++i) {
                const int nn = n0 + c0 + i;
                const float v = (kk < Ksrc && nn < Nsrc) ? src[(size_t)kk * Nsrc + nn] : 0.f;
                tile[r][c0 + i] = f2bf(v);
            }
        }
        __syncthreads();
        {
            const int n = tid >> 2, kc = (tid & 3) << 4;
            if (!(skipHi && (n0 + n) >= 500)) {   // rows 500-511 of W1b owned by blk 4272
                unsigned short* o = dst + (size_t)(n0 + n) * ldDst + k0 + kc;
#pragma unroll
                for (int i = 0; i < 16; ++i) o[i] = tile[kc + i][n];
            }
        }
    } else if (blk == 4272) {
        // ---- P-vector rows ----
#pragma unroll
        for (int q = 0; q < 4; ++q) {
            const int k = tid * 4 + q;
            const float wl = Wl[k];
            const float a1 = cw[k],        a2 = cw[1024 + k], a3 = cw[2048 + k];
            const float d1_ = cw[3072 + k], d2_ = cw[4096 + k], d3_ = cw[5120 + k];
            W1b[(size_t)500 * 1024 + k] = f2bf(a1 * a2 * a3 * wl);
            W1b[(size_t)501 * 1024 + k] = f2bf(a2 * a3 * wl);
            W1b[(size_t)502 * 1024 + k] = f2bf(a3 * wl);
            W1b[(size_t)503 * 1024 + k] = f2bf(d1_ * d2_ * d3_ * wl);
            W1b[(size_t)504 * 1024 + k] = f2bf(d2_ * d3_ * wl);
            W1b[(size_t)505 * 1024 + k] = f2bf(d3_ * wl);
            W1b[(size_t)506 * 1024 + k] = f2bf(wl);
            W1b[(size_t)507 * 1024 + k] = 0x3F80;   // bf16 1.0
            W1b[(size_t)508 * 1024 + k] = 0;
            W1b[(size_t)509 * 1024 + k] = 0;
            W1b[(size_t)510 * 1024 + k] = 0;
            W1b[(size_t)511 * 1024 + k] = 0;
        }
    } else {
        // ---- C scalars (f32 exact) ----
        float c[6] = {0.f, 0.f, 0.f, 0.f, 0.f, 0.f};
#pragma unroll
        for (int q = 0; q < 4; ++q) {
            const int k = tid * 4 + q;
            const float wl = Wl[k];
            {   // task 0
                const float w2 = cw[1024 + k], w3 = cw[2048 + k];
                const float b1 = cb[k], b2 = cb[1024 + k], b3 = cb[2048 + k];
                c[0] += w2 * w3 * b1 * wl;
                c[1] += w3 * b2 * wl;
                c[2] += b3 * wl;
            }
            {   // task 1
                const float w2 = cw[4096 + k], w3 = cw[5120 + k];
                const float b1 = cb[3072 + k], b2 = cb[4096 + k], b3 = cb[5120 + k];
                c[3] += w2 * w3 * b1 * wl;
                c[4] += w3 * b2 * wl;
                c[5] += b3 * wl;
            }
        }
        const int lane = tid & 63, wv = tid >> 6;
#pragma unroll
        for (int j = 0; j < 6; ++j)
#pragma unroll
            for (int m = 1; m < 64; m <<= 1) c[j] += __shfl_xor(c[j], m, 64);
        if (lane == 0)
#pragma unroll
            for (int j = 0; j < 6; ++j) red[wv][j] = c[j];
        __syncthreads();
        if (tid < 6) czz[tid] = red[0][tid] + red[1][tid] + red[2][tid] + red[3][tid];
    }
}

// ---------------------------------------------------------------------------
// stage_tile: global_load_lds dwordx4 with pre-swizzled global source (linear
// LDS dest).  LDS logical layout: row-major [ROWS][64] bf16 (128B/row), with
// 16B chunk c holding global k-chunk (c ^ (row&7)).
// ---------------------------------------------------------------------------
template <int ROWS>
static __device__ __forceinline__ void stage_tile(
    const unsigned short* __restrict__ src, int K, int rowBase, int kt,
    unsigned short* lds, int w, int lane) {
    const int r8   = lane >> 3;
    const int slot = lane & 7;
#pragma unroll
    for (int q = 0; q < ROWS / 32; ++q) {
        const int blk   = q * 4 + w;
        const int row   = blk * 8 + r8;
        const int chunk = slot ^ (row & 7);
        const unsigned short* g = src + (size_t)(rowBase + row) * K + kt * 64 + chunk * 8;
        gload16(g, lds + blk * 512);
    }
}

// ---------------------------------------------------------------------------
// bf16 GEMM1 + bias + ReLU, tile 128 x 128 (m97 structure), BK=64, 4 waves.
// Double-buffered, counted vmcnt, raw s_barrier, XOR-swizzled ds_read_b128.
// Columns 500-507 additionally spill RAW f32 accumulators to zparts
// (cross-net dot products + row-sum from the P/ones columns of W1b).
// ---------------------------------------------------------------------------
template <int BM>
__global__ __launch_bounds__(256) void gemm_bf16(
    const unsigned short* __restrict__ A,    // M x K bf16
    const unsigned short* __restrict__ Bw,   // ldc x K bf16 (N-major)
    const float* __restrict__ bias, int biasN,
    unsigned short* __restrict__ C,          // M x ldc bf16
    float* __restrict__ zparts,              // B_ROWS x 8 f32
    int K, int ldc) {
    constexpr int MREP = BM / 32;
    __shared__ unsigned short As[2][BM * 64];
    __shared__ unsigned short Bs[2][128 * 64];

    const int tid  = threadIdx.x;
    const int lane = tid & 63;
    const int wid  = tid >> 6;
    const int wm   = wid >> 1;
    const int wn   = wid & 1;
    const int g    = lane >> 4;
    const int r16  = lane & 15;

    const int cpx = gridDim.x >> 3;
    const int swz = (blockIdx.x & 7) * cpx + (blockIdx.x >> 3);
    const int nColTiles = ldc >> 7;
    const int rowBase = (swz / nColTiles) * BM;
    const int colBase = (swz % nColTiles) << 7;

    f32x4 acc[MREP][4];
#pragma unroll
    for (int m = 0; m < MREP; ++m)
#pragma unroll
        for (int n = 0; n < 4; ++n)
            acc[m][n] = (f32x4){0.f, 0.f, 0.f, 0.f};

    stage_tile<BM>(A, K, rowBase, 0, As[0], wid, lane);
    stage_tile<128>(Bw, K, colBase, 0, Bs[0], wid, lane);

    const int nK = K >> 6;
    for (int kt = 0; kt < nK; ++kt) {
        const int buf = kt & 1;
        if (kt + 1 < nK) {
            stage_tile<BM>(A, K, rowBase, kt + 1, As[buf ^ 1], wid, lane);
            stage_tile<128>(Bw, K, colBase, kt + 1, Bs[buf ^ 1], wid, lane);
            if constexpr (BM == 128)
                asm volatile("s_waitcnt vmcnt(8)" ::: "memory");
            else
                asm volatile("s_waitcnt vmcnt(6)" ::: "memory");
        } else {
            asm volatile("s_waitcnt vmcnt(0)" ::: "memory");
        }
        __builtin_amdgcn_s_barrier();
        asm volatile("" ::: "memory");

        const unsigned short* Ab = As[buf];
        const unsigned short* Bb = Bs[buf];
#pragma unroll
        for (int ks = 0; ks < 2; ++ks) {
            s16x8 af[MREP], bfr[4];
#pragma unroll
            for (int m = 0; m < MREP; ++m) {
                const int row = wm * (BM / 2) + m * 16 + r16;
                const int off = ((ks * 4 + g) * 16) ^ ((row & 7) << 4);
                af[m] = *(const s16x8*)((const char*)Ab + row * 128 + off);
            }
#pragma unroll
            for (int n = 0; n < 4; ++n) {
                const int row = wn * 64 + n * 16 + r16;
                const int off = ((ks * 4 + g) * 16) ^ ((row & 7) << 4);
                bfr[n] = *(const s16x8*)((const char*)Bb + row * 128 + off);
            }
#pragma unroll
            for (int m = 0; m < MREP; ++m)
#pragma unroll
                for (int n = 0; n < 4; ++n)
                    acc[m][n] = __builtin_amdgcn_mfma_f32_16x16x32_bf16(af[m], bfr[n], acc[m][n], 0, 0, 0);
        }
        asm volatile("s_waitcnt lgkmcnt(0)" ::: "memory");
        __builtin_amdgcn_s_barrier();
        asm volatile("" ::: "memory");
    }

#pragma unroll
    for (int n = 0; n < 4; ++n) {
        const int col = colBase + wn * 64 + n * 16 + r16;
        const float bv = (col < biasN) ? bias[col] : 0.f;
        const unsigned pc = (unsigned)(col - 500);   // cross-dot columns
#pragma unroll
        for (int m = 0; m < MREP; ++m) {
            const int rowB = rowBase + wm * (BM / 2) + m * 16 + g * 4;
#pragma unroll
            for (int r = 0; r < 4; ++r) {
                const float raw = acc[m][n][r];
                float v = raw + bv;
                v = v > 0.f ? v : 0.f;
                C[(size_t)(rowB + r) * ldc + col] = f2bf(v);
                if (pc < 8u) zparts[(size_t)(rowB + r) * 8 + pc] = raw;
            }
        }
    }
}

// ---------------------------------------------------------------------------
// tail_fused: per 64-row block —
//   phase 1: P = relu(d1[64x512] @ W2b^T + b2)  (64x256 bf16 in LDS)
//   phase 2: acc2 = P @ W3b^T
//   epilogue: tail = relu(acc2 + b3) . Wl[1024:]
//   final: z_i = Horner(zparts, s) + czz_i + tail + bl; out = sigmoid(z_i)
// ---------------------------------------------------------------------------
__global__ __launch_bounds__(256) void tail_fused(
    const unsigned short* __restrict__ d1,   // 16384 x 512 bf16
    const unsigned short* __restrict__ W2b,  // 256 x 512 bf16 (N x K)
    const float* __restrict__ b2,
    const unsigned short* __restrict__ W3b,  // 256 x 256 bf16 (N x K)
    const float* __restrict__ b3,
    const float* __restrict__ Wl,            // 1224 floats
    const float* __restrict__ bl,
    const float* __restrict__ zparts,        // B_ROWS x 8
    const float* __restrict__ czz,           // 6
    float* __restrict__ out) {
    __shared__ unsigned short As[2][64 * 64];
    __shared__ unsigned short Bs[2][256 * 64];
    __shared__ unsigned short P[64 * 256];
    __shared__ float part[4][64];

    const int tid  = threadIdx.x;
    const int lane = tid & 63;
    const int wid  = tid >> 6;
    const int g    = lane >> 4;
    const int r16  = lane & 15;
    const int rowBase = blockIdx.x << 6;

    f32x4 acc[4][4];
#pragma unroll
    for (int m = 0; m < 4; ++m)
#pragma unroll
        for (int n = 0; n < 4; ++n)
            acc[m][n] = (f32x4){0.f, 0.f, 0.f, 0.f};

    // ---- phase 1: 64x512 @ W2b (256x512) ----
    stage_tile<64>(d1, 512, rowBase, 0, As[0], wid, lane);
    stage_tile<256>(W2b, 512, 0, 0, Bs[0], wid, lane);

    for (int kt = 0; kt < 8; ++kt) {
        const int buf = kt & 1;
        if (kt + 1 < 8) {
            stage_tile<64>(d1, 512, rowBase, kt + 1, As[buf ^ 1], wid, lane);
            stage_tile<256>(W2b, 512, 0, kt + 1, Bs[buf ^ 1], wid, lane);
            asm volatile("s_waitcnt vmcnt(10)" ::: "memory");
        } else {
            asm volatile("s_waitcnt vmcnt(0)" ::: "memory");
        }
        __builtin_amdgcn_s_barrier();
        asm volatile("" ::: "memory");

        const unsigned short* Ab = As[buf];
        const unsigned short* Bb = Bs[buf];
#pragma unroll
        for (int ks = 0; ks < 2; ++ks) {
            s16x8 af[4], bfr[4];
#pragma unroll
            for (int m = 0; m < 4; ++m) {
                const int row = m * 16 + r16;
                const int off = ((ks * 4 + g) * 16) ^ ((row & 7) << 4);
                af[m] = *(const s16x8*)((const char*)Ab + row * 128 + off);
            }
#pragma unroll
            for (int n = 0; n < 4; ++n) {
                const int row = wid * 64 + n * 16 + r16;
                const int off = ((ks * 4 + g) * 16) ^ ((row & 7) << 4);
                bfr[n] = *(const s16x8*)((const char*)Bb + row * 128 + off);
            }
#pragma unroll
            for (int m = 0; m < 4; ++m)
#pragma unroll
                for (int n = 0; n < 4; ++n)
                    acc[m][n] = __builtin_amdgcn_mfma_f32_16x16x32_bf16(af[m], bfr[n], acc[m][n], 0, 0, 0);
        }
        asm volatile("s_waitcnt lgkmcnt(0)" ::: "memory");
        __builtin_amdgcn_s_barrier();
        asm volatile("" ::: "memory");
    }

    // ---- phase-1 epilogue: bias + relu + bf16 -> P (XOR-swizzled) ----
#pragma unroll
    for (int n = 0; n < 4; ++n) {
        const int col = wid * 64 + n * 16 + r16;
        const float bv = (col < 200) ? b2[col] : 0.f;
#pragma unroll
        for (int m = 0; m < 4; ++m) {
#pragma unroll
            for (int r = 0; r < 4; ++r) {
                const int row = m * 16 + g * 4 + r;
                float v = acc[m][n][r] + bv;
                v = v > 0.f ? v : 0.f;
                const int byte = row * 512 + ((col * 2) ^ ((row & 7) << 4));
                *(unsigned short*)((char*)P + byte) = f2bf(v);
            }
        }
    }

    // ---- phase 2: P (64x256) @ W3b (256x256) ----
    stage_tile<256>(W3b, 256, 0, 0, Bs[0], wid, lane);
    asm volatile("s_waitcnt lgkmcnt(0)" ::: "memory");
    __builtin_amdgcn_s_barrier();
    asm volatile("" ::: "memory");

    f32x4 acc2[4][4];
#pragma unroll
    for (int m = 0; m < 4; ++m)
#pragma unroll
        for (int n = 0; n < 4; ++n)
            acc2[m][n] = (f32x4){0.f, 0.f, 0.f, 0.f};

    for (int kt = 0; kt < 4; ++kt) {
        const int buf = kt & 1;
        if (kt + 1 < 4) {
            stage_tile<256>(W3b, 256, 0, kt + 1, Bs[buf ^ 1], wid, lane);
            asm volatile("s_waitcnt vmcnt(8)" ::: "memory");
        } else {
            asm volatile("s_waitcnt vmcnt(0)" ::: "memory");
        }
        __builtin_amdgcn_s_barrier();
        asm volatile("" ::: "memory");

        const unsigned short* Bb = Bs[buf];
#pragma unroll
        for (int ks = 0; ks < 2; ++ks) {
            s16x8 af[4], bfr[4];
#pragma unroll
            for (int m = 0; m < 4; ++m) {
                const int row = m * 16 + r16;
                const int byte = row * 512 + ((kt * 128 + (ks * 4 + g) * 16) ^ ((row & 7) << 4));
                af[m] = *(const s16x8*)((const char*)P + byte);
            }
#pragma unroll
            for (int n = 0; n < 4; ++n) {
                const int row = wid * 64 + n * 16 + r16;
                const int off = ((ks * 4 + g) * 16) ^ ((row & 7) << 4);
                bfr[n] = *(const s16x8*)((const char*)Bb + row * 128 + off);
            }
#pragma unroll
            for (int m = 0; m < 4; ++m)
#pragma unroll
                for (int n = 0; n < 4; ++n)
                    acc2[m][n] = __builtin_amdgcn_mfma_f32_16x16x32_bf16(af[m], bfr[n], acc2[m][n], 0, 0, 0);
        }
        asm volatile("s_waitcnt lgkmcnt(0)" ::: "memory");
        __builtin_amdgcn_s_barrier();
        asm volatile("" ::: "memory");
    }

    // ---- tail dot ----
    float wlv[4], b3v[4];
#pragma unroll
    for (int n = 0; n < 4; ++n) {
        const int col = wid * 64 + n * 16 + r16;
        wlv[n] = (col < 200) ? Wl[1024 + col] : 0.f;
        b3v[n] = (col < 200) ? b3[col] : 0.f;
    }
#pragma unroll
    for (int m = 0; m < 4; ++m) {
#pragma unroll
        for (int r = 0; r < 4; ++r) {
            float s = 0.f;
#pragma unroll
            for (int n = 0; n < 4; ++n) {
                float v = acc2[m][n][r] + b3v[n];
                v = v > 0.f ? v : 0.f;
                s += v * wlv[n];
            }
            s += __shfl_xor(s, 1, 64);
            s += __shfl_xor(s, 2, 64);
            s += __shfl_xor(s, 4, 64);
            s += __shfl_xor(s, 8, 64);
            if (r16 == 0) part[wid][m * 16 + g * 4 + r] = s;
        }
    }
    __syncthreads();

    // ---- final: cross-net Horner combine + sigmoid ----
    if (tid < 64) {
        const int row = rowBase + tid;
        const float t = part[0][tid] + part[1][tid] + part[2][tid] + part[3][tid];
        const float blv = bl[0];
        const float* zp = zparts + (size_t)row * 8;
        float4 zpa = *(const float4*)(zp);       // P3_0 P2_0 P1_0 P3_1
        float4 zpb = *(const float4*)(zp + 4);   // P2_1 P1_1 P0   s
        const float s = zpb.w;
        const float z0 = ((zpa.x * s + zpa.y + czz[0]) * s + zpa.z + czz[1]) * s
                         + zpb.z + czz[2] + t + blv;
        const float z1 = ((zpa.w * s + zpb.x + czz[3]) * s + zpb.y + czz[4]) * s
                         + zpb.z + czz[5] + t + blv;
        out[row]          = 1.f / (1.f + expf(-z0));
        out[B_ROWS + row] = 1.f / (1.f + expf(-z1));
    }
}

// ---------------------------------------------------------------------------
extern "C" void kernel_launch(void* const* d_in, const int* in_sizes, int n_in,
                              void* d_out, int out_size, void* d_ws, size_t ws_size,
                              hipStream_t stream) {
    const float* x  = (const float*)d_in[0];
    const float* W1 = (const float*)d_in[3];
    const float* b1 = (const float*)d_in[4];
    const float* W2 = (const float*)d_in[5];
    const float* b2 = (const float*)d_in[6];
    const float* W3 = (const float*)d_in[7];
    const float* b3 = (const float*)d_in[8];
    const float* Wl = (const float*)d_in[9];
    const float* bl = (const float*)d_in[10];
    const float* cw = (const float*)d_in[11];
    const float* cb = (const float*)d_in[12];
    float* out = (float*)d_out;

    unsigned short* xb  = (unsigned short*)d_ws;          // 16384 x 1024
    unsigned short* d1  = xb + (size_t)16384 * 1024;      // 16384 x 512
    unsigned short* W1b = d1 + (size_t)16384 * 512;       // 512 x 1024
    unsigned short* W2b = W1b + (size_t)512 * 1024;       // 256 x 512
    unsigned short* W3b = W2b + (size_t)256 * 512;        // 256 x 256
    float* zparts = (float*)(W3b + (size_t)256 * 256);    // 16384 x 8
    float* czz = zparts + (size_t)16384 * 8;              // 6

    // x convert + weight transpose + cross-net P-vectors/constants
    prep<<<4274, 256, 0, stream>>>(x, xb, W1, W2, W3, cw, cb, Wl,
                                   W1b, W2b, W3b, czz);

    // d1 = relu(xb @ W1 + b1); cols 500-507 spill raw cross dots to zparts
    gemm_bf16<128><<<512, 256, 0, stream>>>(xb, W1b, b1, 500, d1, zparts, 1024, 512);

    // d2/d3/tail/cross-combine/sigmoid fused
    tail_fused<<<256, 256, 0, stream>>>(d1, W2b, b2, W3b, b3, Wl, bl,
                                        zparts, czz, out);
}